// Round 8
// baseline (315.442 us; speedup 1.0000x reference)
//
#include <hip/hip_runtime.h>

// Round 27: r26 config verbatim (measured best 251.4us) with ONE change:
// k_combine2cls v2. Budget arithmetic (r19/r20 cross-run): combine ~= 43us
// for ~6us of traffic + ~5us of math. r17's combine staged 25.6MB of
// once-read agg data through 33KB LDS (2 barriers) at ~150 VGPR (3 waves/
// SIMD). v2 keeps the register-weight inner loop but reads agg/h1 rows
// DIRECTLY from global at lane-uniform addresses (32 j-lanes share each 16B
// address -> single request + broadcast, L1-hot). LDS 33.5KB -> 9.5KB, one
// barrier. Everything else untouched.
//
// ws: aggT[N*32] aggI[N*32] f32 | h1b[N*32] xp[N*8] bf16 | curT curI |
//     startT degT midT startI degI midI [N] | binT binI [K*CAP] int |
//     csrT csrI [K*CAP] ushort

#define BLK 256
#define RN 512            // nodes per bucket
#define KMAX 256          // max buckets (N <= 131072)
#define CAP 11264         // bucket capacity (mean 10204, +10 sigma)
#define CHUNK 4096        // edges per bin3 block

typedef unsigned short us8 __attribute__((ext_vector_type(8)));

__device__ inline unsigned short f2bf(float f) {
  unsigned u = __float_as_uint(f);
  return (unsigned short)((u + 0x7FFFu + ((u >> 16) & 1u)) >> 16);
}
__device__ inline float bf2f(unsigned short h) {
  return __uint_as_float(((unsigned)h) << 16);
}

// ---------------- prep: x -> bf16 padded rows; init bucket cursors ----------
__global__ __launch_bounds__(BLK) void k_prep(const float* __restrict__ x,
                                              unsigned short* __restrict__ xp,
                                              int* __restrict__ curT,
                                              int* __restrict__ curI, int N,
                                              int K) {
  int gid = blockIdx.x * BLK + threadIdx.x;
  if (gid < K) {
    curT[gid] = gid * CAP;
    curI[gid] = gid * CAP;
  }
  if (gid >= N * 8) return;
  int n = gid >> 3, c = gid & 7;
  xp[gid] = (c < 6) ? f2bf(x[n * 6 + c]) : (unsigned short)0;
}

// ---------------- bin: LDS-staged local sort, coalesced run writes ----------
__global__ __launch_bounds__(BLK) void k_bin3(
    const int* __restrict__ eiT, int ET, int* __restrict__ curT,
    int* __restrict__ binT, const int* __restrict__ eiI, int EI,
    int* __restrict__ curI, int* __restrict__ binI, int K) {
  const int* ei = blockIdx.y ? eiI : eiT;
  int E = blockIdx.y ? EI : ET;
  int* gcur = blockIdx.y ? curI : curT;
  int* binned = blockIdx.y ? binI : binT;
  int cs = blockIdx.x * CHUNK;
  if (cs >= E) return;
  int ce = min(E, cs + CHUNK);
  int cnt = ce - cs;
  __shared__ int ebuf[CHUNK];
  __shared__ unsigned char bbuf[CHUNK];
  __shared__ int hist[KMAX], cur[KMAX], gdelta[KMAX], s[KMAX];
  int t = threadIdx.x;
  hist[t] = 0;
  __syncthreads();
  for (int e = cs + t; e < ce; e += BLK) atomicAdd(&hist[ei[E + e] >> 9], 1);
  __syncthreads();
  int v = hist[t];
  s[t] = v;
  __syncthreads();
  for (int off = 1; off < KMAX; off <<= 1) {
    int x = (t >= off) ? s[t - off] : 0;
    __syncthreads();
    s[t] += x;
    __syncthreads();
  }
  int excl = s[t] - v;
  cur[t] = excl;
  if (t < K) gdelta[t] = atomicAdd(&gcur[t], v) - excl;
  __syncthreads();
  for (int e = cs + t; e < ce; e += BLK) {
    int src = ei[e];
    int d = ei[E + e];
    int b = d >> 9;
    int slot = atomicAdd(&cur[b], 1);
    ebuf[slot] = (src << 9) | (d & 511);
    bbuf[slot] = (unsigned char)b;
  }
  __syncthreads();
  for (int i = t; i < cnt; i += BLK) {
    int b = bbuf[i];
    __builtin_nontemporal_store(ebuf[i], &binned[i + gdelta[b]]);
  }
}

// per-bucket counting sort, (node, src-half) keys -> 16-bit csr + start/deg/mid
__global__ __launch_bounds__(512) void k_sortcsr2m(
    const int* __restrict__ binT, const int* __restrict__ curT,
    unsigned short* __restrict__ csrT, int* __restrict__ startT,
    int* __restrict__ degT, int* __restrict__ midT,
    const int* __restrict__ binI, const int* __restrict__ curI,
    unsigned short* __restrict__ csrI, int* __restrict__ startI,
    int* __restrict__ degI, int* __restrict__ midI, int N, int halfN) {
  const int* bin = blockIdx.y ? binI : binT;
  const int* cur = blockIdx.y ? curI : curT;
  unsigned short* csr = blockIdx.y ? csrI : csrT;
  int* start = blockIdx.y ? startI : startT;
  int* deg = blockIdx.y ? degI : degT;
  int* mid = blockIdx.y ? midI : midT;
  __shared__ int h[2 * RN], s[RN], c2[2 * RN];
  int t = threadIdx.x, b = blockIdx.x;
  int e0 = b * CAP;
  int cnt = min(cur[b] - e0, CAP);
  h[t] = 0;
  h[t + RN] = 0;
  __syncthreads();
  for (int i = t; i < cnt; i += 512) {
    int p = bin[e0 + i];
    int key = ((p & 511) << 1) | ((p >> 9) >= halfN ? 1 : 0);
    atomicAdd(&h[key], 1);
  }
  __syncthreads();
  int lo = h[2 * t], hi = h[2 * t + 1];
  int pair = lo + hi;
  s[t] = pair;
  __syncthreads();
  for (int off = 1; off < 512; off <<= 1) {
    int v = (t >= off) ? s[t - off] : 0;
    __syncthreads();
    s[t] += v;
    __syncthreads();
  }
  int excl = s[t] - pair;
  c2[2 * t] = excl;
  c2[2 * t + 1] = excl + lo;
  int n = b * RN + t;
  if (n < N) {
    start[n] = e0 + excl;
    deg[n] = pair;
    mid[n] = e0 + excl + lo;
  }
  __syncthreads();
  for (int i = t; i < cnt; i += 512) {
    int p = bin[e0 + i];
    int src = p >> 9;
    int hiFlag = (src >= halfN) ? 1 : 0;
    int key = ((p & 511) << 1) | hiFlag;
    int pos = atomicAdd(&c2[key], 1);
    csr[e0 + pos] = (unsigned short)(src - hiFlag * halfN);
  }
}

// ------- fused layer 1: 8 thr/node (etype x src-half x edge-parity),
//         full 16B row loads (one VMEM request per edge) ----------
#define GN1 32
__global__ __launch_bounds__(BLK) void k_g1c1(
    const unsigned short* __restrict__ xp, const float* __restrict__ x,
    const int* __restrict__ startT, const int* __restrict__ degT,
    const int* __restrict__ midT, const unsigned short* __restrict__ csrT,
    const int* __restrict__ startI, const int* __restrict__ degI,
    const int* __restrict__ midI, const unsigned short* __restrict__ csrI,
    const float* __restrict__ Wt, const float* __restrict__ bt,
    const float* __restrict__ Wi, const float* __restrict__ bi,
    const float* __restrict__ Wr, const float* __restrict__ br,
    unsigned short* __restrict__ h1b, int N, int halfN) {
  __shared__ float sGT[GN1 * 32], sGI[GN1 * 32], sx[GN1 * 6];
  __shared__ float sWt[192], sWi[192], sWr[192], sb[96];
  __shared__ float sdT[GN1], sdI[GN1];
  int t = threadIdx.x, b = blockIdx.x;
  if (t < 192) { sWt[t] = Wt[t]; sWi[t] = Wi[t]; sWr[t] = Wr[t]; }
  if (t < 32) { sb[t] = bt[t]; sb[32 + t] = bi[t]; sb[64 + t] = br[t]; }
  if (t < GN1 * 6) {
    int g = b * GN1 * 6 + t;
    sx[t] = (g < N * 6) ? x[g] : 0.0f;
  }
  int nl = t >> 3, et = (t >> 2) & 1, half = (t >> 1) & 1, par = t & 1;
  int n = b * GN1 + nl;
  float a[8] = {0.f, 0.f, 0.f, 0.f, 0.f, 0.f, 0.f, 0.f};
  int d = 0;
  if (n < N) {
    const int* startA = et ? startI : startT;
    const int* degA = et ? degI : degT;
    const int* midA = et ? midI : midT;
    const unsigned short* csrA = et ? csrI : csrT;
    int s0 = startA[n];
    d = degA[n];
    int m = midA[n];
    int i0 = half ? m : s0;
    int i1 = half ? (s0 + d) : m;
    const unsigned short* tab = xp + (half ? (size_t)halfN * 8 : 0);
    int i = i0 + par;
    for (; i + 6 < i1; i += 8) {
      int r0 = csrA[i], r1 = csrA[i + 2], r2 = csrA[i + 4], r3 = csrA[i + 6];
      us8 v0 = *(const us8*)(tab + (size_t)r0 * 8);
      us8 v1 = *(const us8*)(tab + (size_t)r1 * 8);
      us8 v2 = *(const us8*)(tab + (size_t)r2 * 8);
      us8 v3 = *(const us8*)(tab + (size_t)r3 * 8);
#pragma unroll
      for (int k = 0; k < 8; ++k)
        a[k] += (bf2f(v0[k]) + bf2f(v1[k])) + (bf2f(v2[k]) + bf2f(v3[k]));
    }
    for (; i < i1; i += 2) {
      int r0 = csrA[i];
      us8 v0 = *(const us8*)(tab + (size_t)r0 * 8);
#pragma unroll
      for (int k = 0; k < 8; ++k) a[k] += bf2f(v0[k]);
    }
  }
  // slot = half*2 + par; 4 slots x 8ch = 32 floats per (node, etype)
  float* dst = (et ? sGI : sGT) + nl * 32 + (half * 2 + par) * 8;
#pragma unroll
  for (int k = 0; k < 8; ++k) dst[k] = a[k];
  if (half == 0 && par == 0) {
    if (et) sdI[nl] = (float)d;
    else    sdT[nl] = (float)d;
  }
  __syncthreads();
  for (int idx = t; idx < GN1 * 32; idx += BLK) {
    int m = idx >> 5, j = idx & 31;
    int nn = b * GN1 + m;
    if (nn >= N) break;
    float fdT = sdT[m], fdI = sdI[m];
    float invI = 1.0f / fmaxf(fdI, 1.0f);
    float gate = (fdI > 0.0f) ? 1.0f : 0.0f;
    float acc = fdT * sb[j] + gate * sb[32 + j] + sb[64 + j];
#pragma unroll
    for (int k = 0; k < 6; ++k) {
      float gT = sGT[m * 32 + k] + sGT[m * 32 + 8 + k] +
                 sGT[m * 32 + 16 + k] + sGT[m * 32 + 24 + k];
      float gI = sGI[m * 32 + k] + sGI[m * 32 + 8 + k] +
                 sGI[m * 32 + 16 + k] + sGI[m * 32 + 24 + k];
      acc += gT * sWt[k * 32 + j];
      acc += gI * invI * sWi[k * 32 + j];
      acc += sx[m * 6 + k] * sWr[k * 32 + j];
    }
    h1b[(size_t)nn * 32 + j] = f2bf(fmaxf(acc, 0.0f));
  }
}

// ---------------- layer-2 gather helper: unroll-4, 16B bf16 loads ----------
__device__ inline void accum8(const unsigned short* __restrict__ tab,
                              const unsigned short* __restrict__ csr, int i0,
                              int i1, float* a) {
  int i = i0;
  for (; i + 4 <= i1; i += 4) {
    int r0 = csr[i], r1 = csr[i + 1], r2 = csr[i + 2], r3 = csr[i + 3];
    us8 v0 = *(const us8*)(tab + (size_t)r0 * 32);
    us8 v1 = *(const us8*)(tab + (size_t)r1 * 32);
    us8 v2 = *(const us8*)(tab + (size_t)r2 * 32);
    us8 v3 = *(const us8*)(tab + (size_t)r3 * 32);
#pragma unroll
    for (int k = 0; k < 8; ++k)
      a[k] += (bf2f(v0[k]) + bf2f(v1[k])) + (bf2f(v2[k]) + bf2f(v3[k]));
  }
  for (; i < i1; ++i) {
    int r0 = csr[i];
    us8 v0 = *(const us8*)(tab + (size_t)r0 * 32);
#pragma unroll
    for (int k = 0; k < 8; ++k) a[k] += bf2f(v0[k]);
  }
}

// --- layer-2 gather: 4 thr/node (chan-quarter), src-half phased (r19) ------
__global__ __launch_bounds__(BLK) void k_gather2(
    const unsigned short* __restrict__ h1b, const int* __restrict__ startT,
    const int* __restrict__ degT, const int* __restrict__ midT,
    const unsigned short* __restrict__ csrT, const int* __restrict__ startI,
    const int* __restrict__ degI, const int* __restrict__ midI,
    const unsigned short* __restrict__ csrI, float* __restrict__ aggT,
    float* __restrict__ aggI, int N, int halfN) {
  const int* start = blockIdx.y ? startI : startT;
  const int* deg = blockIdx.y ? degI : degT;
  const int* mid = blockIdx.y ? midI : midT;
  const unsigned short* csr = blockIdx.y ? csrI : csrT;
  float* agg = blockIdx.y ? aggI : aggT;
  int gid = blockIdx.x * BLK + threadIdx.x;
  int n = gid >> 2;
  if (n >= N) return;
  int c8 = (gid & 3) * 8;
  float a[8] = {0.f, 0.f, 0.f, 0.f, 0.f, 0.f, 0.f, 0.f};
  int s0 = start[n], d = deg[n], m = mid[n];
  // phase 0: src < N/2 (lower table half L2-resident chip-wide), then phase 1
  accum8(h1b + c8, csr, s0, m, a);
  accum8(h1b + (size_t)halfN * 32 + c8, csr, m, s0 + d, a);
  float* p = agg + (size_t)n * 32 + c8;
#pragma unroll
  for (int k = 0; k < 8; ++k) __builtin_nontemporal_store(a[k], p + k);
}

// ------- combine2 + classifier v2: no agg LDS staging, direct uniform
//         global reads (auto-broadcast), reg weights, one barrier ----------
#define CN 64
__global__ __launch_bounds__(BLK) void k_combine2cls(
    const float* __restrict__ aggT, const float* __restrict__ aggI,
    const unsigned short* __restrict__ h1b, const int* __restrict__ degT,
    const int* __restrict__ degI, const float* __restrict__ Wt,
    const float* __restrict__ bt, const float* __restrict__ Wi,
    const float* __restrict__ bi, const float* __restrict__ Wr,
    const float* __restrict__ br, const float* __restrict__ Wc,
    const float* __restrict__ bc, float* __restrict__ out, int N) {
  __shared__ float hs2[CN * 32];
  __shared__ float sWc[224], sbc[7], sb[96];
  int t = threadIdx.x;
  int j = t & 31, ln = t >> 5;
  float wt[32], wi[32], wr[32];
#pragma unroll
  for (int k = 0; k < 32; ++k) {
    wt[k] = Wt[k * 32 + j];
    wi[k] = Wi[k * 32 + j];
    wr[k] = Wr[k * 32 + j];
  }
  if (t < 224) sWc[t] = Wc[t];
  if (t < 7) sbc[t] = bc[t];
  if (t < 32) { sb[t] = bt[t]; sb[32 + t] = bi[t]; sb[64 + t] = br[t]; }
  int node0 = blockIdx.x * CN;
  __syncthreads();
#pragma unroll
  for (int it = 0; it < CN / 8; ++it) {
    int li = it * 8 + ln;
    int n = node0 + li;
    if (n < N) {
      float dT = (float)degT[n], dI = (float)degI[n];
      float invI = 1.0f / fmaxf(dI, 1.0f);
      float gate = (dI > 0.0f) ? 1.0f : 0.0f;
      // lane-uniform addresses within each 32-lane j-group: single request
      // + broadcast; L1-hot across the 8 ln-groups.
      const float4* hT4 = (const float4*)(aggT + (size_t)n * 32);
      const float4* hI4 = (const float4*)(aggI + (size_t)n * 32);
      const us8* hR8 = (const us8*)(h1b + (size_t)n * 32);
      float aT = 0.f, aI = 0.f, aR = 0.f;
#pragma unroll
      for (int kk = 0; kk < 8; ++kk) {
        float4 a = hT4[kk], bI = hI4[kk];
        aT += a.x * wt[kk * 4 + 0] + a.y * wt[kk * 4 + 1] +
              a.z * wt[kk * 4 + 2] + a.w * wt[kk * 4 + 3];
        aI += bI.x * wi[kk * 4 + 0] + bI.y * wi[kk * 4 + 1] +
              bI.z * wi[kk * 4 + 2] + bI.w * wi[kk * 4 + 3];
      }
#pragma unroll
      for (int kk = 0; kk < 4; ++kk) {
        us8 v = hR8[kk];
        aR += bf2f(v[0]) * wr[kk * 8 + 0] + bf2f(v[1]) * wr[kk * 8 + 1] +
              bf2f(v[2]) * wr[kk * 8 + 2] + bf2f(v[3]) * wr[kk * 8 + 3] +
              bf2f(v[4]) * wr[kk * 8 + 4] + bf2f(v[5]) * wr[kk * 8 + 5] +
              bf2f(v[6]) * wr[kk * 8 + 6] + bf2f(v[7]) * wr[kk * 8 + 7];
      }
      float acc =
          dT * sb[j] + gate * sb[32 + j] + sb[64 + j] + aT + invI * aI + aR;
      hs2[li * 32 + j] = fmaxf(acc, 0.0f);
    }
  }
  __syncthreads();
  if (t < 224) {
#pragma unroll
    for (int pass = 0; pass < CN * 7 / 224; ++pass) {
      int o = pass * 224 + t;
      int m = o / 7, jc = o - m * 7;
      int n = node0 + m;
      if (n < N) {
        float a = sbc[jc];
        const float* hp = hs2 + m * 32;
#pragma unroll
        for (int k = 0; k < 32; ++k) a += hp[k] * sWc[k * 7 + jc];
        out[(size_t)n * 7 + jc] = a;
      }
    }
  }
}

extern "C" void kernel_launch(void* const* d_in, const int* in_sizes, int n_in,
                              void* d_out, int out_size, void* d_ws,
                              size_t ws_size, hipStream_t stream) {
  const float* x   = (const float*)d_in[0];
  const int* ei_t  = (const int*)d_in[1];
  const int* ei_i  = (const int*)d_in[2];
  const float* W1t = (const float*)d_in[3];
  const float* b1t = (const float*)d_in[4];
  const float* W1i = (const float*)d_in[5];
  const float* b1i = (const float*)d_in[6];
  const float* W1r = (const float*)d_in[7];
  const float* b1r = (const float*)d_in[8];
  const float* W2t = (const float*)d_in[9];
  const float* b2t = (const float*)d_in[10];
  const float* W2i = (const float*)d_in[11];
  const float* b2i = (const float*)d_in[12];
  const float* W2r = (const float*)d_in[13];
  const float* b2r = (const float*)d_in[14];
  const float* Wc  = (const float*)d_in[15];
  const float* bc  = (const float*)d_in[16];
  float* out = (float*)d_out;

  const int N  = in_sizes[0] / 6;
  const int E  = in_sizes[1] / 2;
  const int Ei = in_sizes[2] / 2;
  const int K  = (N + RN - 1) / RN;
  const int halfN = N >> 1;   // halves must fit ushort: N <= 131070

  float* aggT = (float*)d_ws;
  float* aggI = aggT + (size_t)N * 32;
  unsigned short* h1b = (unsigned short*)(aggI + (size_t)N * 32);
  unsigned short* xp  = h1b + (size_t)N * 32;
  int* curT   = (int*)(xp + (size_t)N * 8);
  int* curI   = curT + KMAX;
  int* startT = curI + KMAX;
  int* degT   = startT + N;
  int* midT   = degT + N;
  int* startI = midT + N;
  int* degI   = startI + N;
  int* midI   = degI + N;
  int* binT   = midI + N;
  int* binI   = binT + (size_t)K * CAP;
  unsigned short* csrT = (unsigned short*)(binI + (size_t)K * CAP);
  unsigned short* csrI = csrT + (size_t)K * CAP;

  const int gN8  = (N * 8 + BLK - 1) / BLK;
  const int gG1  = (N + GN1 - 1) / GN1;
  const int gG2  = (N * 4 + BLK - 1) / BLK;
  const int gC2  = (N + CN - 1) / CN;
  const int Emax = (E > Ei) ? E : Ei;
  const int gBin = (Emax + CHUNK - 1) / CHUNK;

  // ---- build ----
  k_prep<<<gN8, BLK, 0, stream>>>(x, xp, curT, curI, N, K);
  k_bin3<<<dim3(gBin, 2), BLK, 0, stream>>>(ei_t, E, curT, binT, ei_i, Ei,
                                            curI, binI, K);
  k_sortcsr2m<<<dim3(K, 2), 512, 0, stream>>>(binT, curT, csrT, startT, degT,
                                              midT, binI, curI, csrI, startI,
                                              degI, midI, N, halfN);

  // ---- Layer 1 (fused gather+transform -> bf16 h1, 16B row loads) ----
  k_g1c1<<<gG1, BLK, 0, stream>>>(xp, x, startT, degT, midT, csrT, startI,
                                  degI, midI, csrI, W1t, b1t, W1i, b1i, W1r,
                                  b1r, h1b, N, halfN);

  // ---- Layer 2 (src-half phased gather, then combine v2 + cls) ----
  k_gather2<<<dim3(gG2, 2), BLK, 0, stream>>>(h1b, startT, degT, midT, csrT,
                                              startI, degI, midI, csrI, aggT,
                                              aggI, N, halfN);
  k_combine2cls<<<gC2, BLK, 0, stream>>>(aggT, aggI, h1b, degT, degI, W2t,
                                         b2t, W2i, b2i, W2r, b2r, Wc, bc, out,
                                         N);
}

// Round 9
// 251.752 us; speedup vs baseline: 1.2530x; 1.2530x over previous
//
#include <hip/hip_runtime.h>

// Round 28: r26 config verbatim (measured best 251.4us) with combine v3.
// r27 post-mortem: combine v2 at VGPR=76 -> compiler SPILLED the 96-reg
// weight arrays to scratch (95us, HBM 2.5%). v3 inverts the placement:
// WEIGHTS in LDS (float4 lane-uniform broadcast reads, conflict-free),
// DATA in registers. One thread per node: stream aggT/aggI/h1 rows into
// 32 regs (sequentially reused, statically indexed), 3x 32x32 matvec,
// ReLU, classifier, 7-float store. One barrier, ~13KB LDS, ~80 VGPR.
//
// ws: aggT[N*32] aggI[N*32] f32 | h1b[N*32] xp[N*8] bf16 | curT curI |
//     startT degT midT startI degI midI [N] | binT binI [K*CAP] int |
//     csrT csrI [K*CAP] ushort

#define BLK 256
#define RN 512            // nodes per bucket
#define KMAX 256          // max buckets (N <= 131072)
#define CAP 11264         // bucket capacity (mean 10204, +10 sigma)
#define CHUNK 4096        // edges per bin3 block

typedef unsigned short us8 __attribute__((ext_vector_type(8)));

__device__ inline unsigned short f2bf(float f) {
  unsigned u = __float_as_uint(f);
  return (unsigned short)((u + 0x7FFFu + ((u >> 16) & 1u)) >> 16);
}
__device__ inline float bf2f(unsigned short h) {
  return __uint_as_float(((unsigned)h) << 16);
}

// ---------------- prep: x -> bf16 padded rows; init bucket cursors ----------
__global__ __launch_bounds__(BLK) void k_prep(const float* __restrict__ x,
                                              unsigned short* __restrict__ xp,
                                              int* __restrict__ curT,
                                              int* __restrict__ curI, int N,
                                              int K) {
  int gid = blockIdx.x * BLK + threadIdx.x;
  if (gid < K) {
    curT[gid] = gid * CAP;
    curI[gid] = gid * CAP;
  }
  if (gid >= N * 8) return;
  int n = gid >> 3, c = gid & 7;
  xp[gid] = (c < 6) ? f2bf(x[n * 6 + c]) : (unsigned short)0;
}

// ---------------- bin: LDS-staged local sort, coalesced run writes ----------
__global__ __launch_bounds__(BLK) void k_bin3(
    const int* __restrict__ eiT, int ET, int* __restrict__ curT,
    int* __restrict__ binT, const int* __restrict__ eiI, int EI,
    int* __restrict__ curI, int* __restrict__ binI, int K) {
  const int* ei = blockIdx.y ? eiI : eiT;
  int E = blockIdx.y ? EI : ET;
  int* gcur = blockIdx.y ? curI : curT;
  int* binned = blockIdx.y ? binI : binT;
  int cs = blockIdx.x * CHUNK;
  if (cs >= E) return;
  int ce = min(E, cs + CHUNK);
  int cnt = ce - cs;
  __shared__ int ebuf[CHUNK];
  __shared__ unsigned char bbuf[CHUNK];
  __shared__ int hist[KMAX], cur[KMAX], gdelta[KMAX], s[KMAX];
  int t = threadIdx.x;
  hist[t] = 0;
  __syncthreads();
  for (int e = cs + t; e < ce; e += BLK) atomicAdd(&hist[ei[E + e] >> 9], 1);
  __syncthreads();
  int v = hist[t];
  s[t] = v;
  __syncthreads();
  for (int off = 1; off < KMAX; off <<= 1) {
    int x = (t >= off) ? s[t - off] : 0;
    __syncthreads();
    s[t] += x;
    __syncthreads();
  }
  int excl = s[t] - v;
  cur[t] = excl;
  if (t < K) gdelta[t] = atomicAdd(&gcur[t], v) - excl;
  __syncthreads();
  for (int e = cs + t; e < ce; e += BLK) {
    int src = ei[e];
    int d = ei[E + e];
    int b = d >> 9;
    int slot = atomicAdd(&cur[b], 1);
    ebuf[slot] = (src << 9) | (d & 511);
    bbuf[slot] = (unsigned char)b;
  }
  __syncthreads();
  for (int i = t; i < cnt; i += BLK) {
    int b = bbuf[i];
    __builtin_nontemporal_store(ebuf[i], &binned[i + gdelta[b]]);
  }
}

// per-bucket counting sort, (node, src-half) keys -> 16-bit csr + start/deg/mid
__global__ __launch_bounds__(512) void k_sortcsr2m(
    const int* __restrict__ binT, const int* __restrict__ curT,
    unsigned short* __restrict__ csrT, int* __restrict__ startT,
    int* __restrict__ degT, int* __restrict__ midT,
    const int* __restrict__ binI, const int* __restrict__ curI,
    unsigned short* __restrict__ csrI, int* __restrict__ startI,
    int* __restrict__ degI, int* __restrict__ midI, int N, int halfN) {
  const int* bin = blockIdx.y ? binI : binT;
  const int* cur = blockIdx.y ? curI : curT;
  unsigned short* csr = blockIdx.y ? csrI : csrT;
  int* start = blockIdx.y ? startI : startT;
  int* deg = blockIdx.y ? degI : degT;
  int* mid = blockIdx.y ? midI : midT;
  __shared__ int h[2 * RN], s[RN], c2[2 * RN];
  int t = threadIdx.x, b = blockIdx.x;
  int e0 = b * CAP;
  int cnt = min(cur[b] - e0, CAP);
  h[t] = 0;
  h[t + RN] = 0;
  __syncthreads();
  for (int i = t; i < cnt; i += 512) {
    int p = bin[e0 + i];
    int key = ((p & 511) << 1) | ((p >> 9) >= halfN ? 1 : 0);
    atomicAdd(&h[key], 1);
  }
  __syncthreads();
  int lo = h[2 * t], hi = h[2 * t + 1];
  int pair = lo + hi;
  s[t] = pair;
  __syncthreads();
  for (int off = 1; off < 512; off <<= 1) {
    int v = (t >= off) ? s[t - off] : 0;
    __syncthreads();
    s[t] += v;
    __syncthreads();
  }
  int excl = s[t] - pair;
  c2[2 * t] = excl;
  c2[2 * t + 1] = excl + lo;
  int n = b * RN + t;
  if (n < N) {
    start[n] = e0 + excl;
    deg[n] = pair;
    mid[n] = e0 + excl + lo;
  }
  __syncthreads();
  for (int i = t; i < cnt; i += 512) {
    int p = bin[e0 + i];
    int src = p >> 9;
    int hiFlag = (src >= halfN) ? 1 : 0;
    int key = ((p & 511) << 1) | hiFlag;
    int pos = atomicAdd(&c2[key], 1);
    csr[e0 + pos] = (unsigned short)(src - hiFlag * halfN);
  }
}

// ------- fused layer 1: 8 thr/node (etype x src-half x edge-parity),
//         full 16B row loads (one VMEM request per edge) ----------
#define GN1 32
__global__ __launch_bounds__(BLK) void k_g1c1(
    const unsigned short* __restrict__ xp, const float* __restrict__ x,
    const int* __restrict__ startT, const int* __restrict__ degT,
    const int* __restrict__ midT, const unsigned short* __restrict__ csrT,
    const int* __restrict__ startI, const int* __restrict__ degI,
    const int* __restrict__ midI, const unsigned short* __restrict__ csrI,
    const float* __restrict__ Wt, const float* __restrict__ bt,
    const float* __restrict__ Wi, const float* __restrict__ bi,
    const float* __restrict__ Wr, const float* __restrict__ br,
    unsigned short* __restrict__ h1b, int N, int halfN) {
  __shared__ float sGT[GN1 * 32], sGI[GN1 * 32], sx[GN1 * 6];
  __shared__ float sWt[192], sWi[192], sWr[192], sb[96];
  __shared__ float sdT[GN1], sdI[GN1];
  int t = threadIdx.x, b = blockIdx.x;
  if (t < 192) { sWt[t] = Wt[t]; sWi[t] = Wi[t]; sWr[t] = Wr[t]; }
  if (t < 32) { sb[t] = bt[t]; sb[32 + t] = bi[t]; sb[64 + t] = br[t]; }
  if (t < GN1 * 6) {
    int g = b * GN1 * 6 + t;
    sx[t] = (g < N * 6) ? x[g] : 0.0f;
  }
  int nl = t >> 3, et = (t >> 2) & 1, half = (t >> 1) & 1, par = t & 1;
  int n = b * GN1 + nl;
  float a[8] = {0.f, 0.f, 0.f, 0.f, 0.f, 0.f, 0.f, 0.f};
  int d = 0;
  if (n < N) {
    const int* startA = et ? startI : startT;
    const int* degA = et ? degI : degT;
    const int* midA = et ? midI : midT;
    const unsigned short* csrA = et ? csrI : csrT;
    int s0 = startA[n];
    d = degA[n];
    int m = midA[n];
    int i0 = half ? m : s0;
    int i1 = half ? (s0 + d) : m;
    const unsigned short* tab = xp + (half ? (size_t)halfN * 8 : 0);
    int i = i0 + par;
    for (; i + 6 < i1; i += 8) {
      int r0 = csrA[i], r1 = csrA[i + 2], r2 = csrA[i + 4], r3 = csrA[i + 6];
      us8 v0 = *(const us8*)(tab + (size_t)r0 * 8);
      us8 v1 = *(const us8*)(tab + (size_t)r1 * 8);
      us8 v2 = *(const us8*)(tab + (size_t)r2 * 8);
      us8 v3 = *(const us8*)(tab + (size_t)r3 * 8);
#pragma unroll
      for (int k = 0; k < 8; ++k)
        a[k] += (bf2f(v0[k]) + bf2f(v1[k])) + (bf2f(v2[k]) + bf2f(v3[k]));
    }
    for (; i < i1; i += 2) {
      int r0 = csrA[i];
      us8 v0 = *(const us8*)(tab + (size_t)r0 * 8);
#pragma unroll
      for (int k = 0; k < 8; ++k) a[k] += bf2f(v0[k]);
    }
  }
  // slot = half*2 + par; 4 slots x 8ch = 32 floats per (node, etype)
  float* dst = (et ? sGI : sGT) + nl * 32 + (half * 2 + par) * 8;
#pragma unroll
  for (int k = 0; k < 8; ++k) dst[k] = a[k];
  if (half == 0 && par == 0) {
    if (et) sdI[nl] = (float)d;
    else    sdT[nl] = (float)d;
  }
  __syncthreads();
  for (int idx = t; idx < GN1 * 32; idx += BLK) {
    int m = idx >> 5, j = idx & 31;
    int nn = b * GN1 + m;
    if (nn >= N) break;
    float fdT = sdT[m], fdI = sdI[m];
    float invI = 1.0f / fmaxf(fdI, 1.0f);
    float gate = (fdI > 0.0f) ? 1.0f : 0.0f;
    float acc = fdT * sb[j] + gate * sb[32 + j] + sb[64 + j];
#pragma unroll
    for (int k = 0; k < 6; ++k) {
      float gT = sGT[m * 32 + k] + sGT[m * 32 + 8 + k] +
                 sGT[m * 32 + 16 + k] + sGT[m * 32 + 24 + k];
      float gI = sGI[m * 32 + k] + sGI[m * 32 + 8 + k] +
                 sGI[m * 32 + 16 + k] + sGI[m * 32 + 24 + k];
      acc += gT * sWt[k * 32 + j];
      acc += gI * invI * sWi[k * 32 + j];
      acc += sx[m * 6 + k] * sWr[k * 32 + j];
    }
    h1b[(size_t)nn * 32 + j] = f2bf(fmaxf(acc, 0.0f));
  }
}

// ---------------- layer-2 gather helper: unroll-4, 16B bf16 loads ----------
__device__ inline void accum8(const unsigned short* __restrict__ tab,
                              const unsigned short* __restrict__ csr, int i0,
                              int i1, float* a) {
  int i = i0;
  for (; i + 4 <= i1; i += 4) {
    int r0 = csr[i], r1 = csr[i + 1], r2 = csr[i + 2], r3 = csr[i + 3];
    us8 v0 = *(const us8*)(tab + (size_t)r0 * 32);
    us8 v1 = *(const us8*)(tab + (size_t)r1 * 32);
    us8 v2 = *(const us8*)(tab + (size_t)r2 * 32);
    us8 v3 = *(const us8*)(tab + (size_t)r3 * 32);
#pragma unroll
    for (int k = 0; k < 8; ++k)
      a[k] += (bf2f(v0[k]) + bf2f(v1[k])) + (bf2f(v2[k]) + bf2f(v3[k]));
  }
  for (; i < i1; ++i) {
    int r0 = csr[i];
    us8 v0 = *(const us8*)(tab + (size_t)r0 * 32);
#pragma unroll
    for (int k = 0; k < 8; ++k) a[k] += bf2f(v0[k]);
  }
}

// --- layer-2 gather: 4 thr/node (chan-quarter), src-half phased (r19) ------
__global__ __launch_bounds__(BLK) void k_gather2(
    const unsigned short* __restrict__ h1b, const int* __restrict__ startT,
    const int* __restrict__ degT, const int* __restrict__ midT,
    const unsigned short* __restrict__ csrT, const int* __restrict__ startI,
    const int* __restrict__ degI, const int* __restrict__ midI,
    const unsigned short* __restrict__ csrI, float* __restrict__ aggT,
    float* __restrict__ aggI, int N, int halfN) {
  const int* start = blockIdx.y ? startI : startT;
  const int* deg = blockIdx.y ? degI : degT;
  const int* mid = blockIdx.y ? midI : midT;
  const unsigned short* csr = blockIdx.y ? csrI : csrT;
  float* agg = blockIdx.y ? aggI : aggT;
  int gid = blockIdx.x * BLK + threadIdx.x;
  int n = gid >> 2;
  if (n >= N) return;
  int c8 = (gid & 3) * 8;
  float a[8] = {0.f, 0.f, 0.f, 0.f, 0.f, 0.f, 0.f, 0.f};
  int s0 = start[n], d = deg[n], m = mid[n];
  // phase 0: src < N/2 (lower table half L2-resident chip-wide), then phase 1
  accum8(h1b + c8, csr, s0, m, a);
  accum8(h1b + (size_t)halfN * 32 + c8, csr, m, s0 + d, a);
  float* p = agg + (size_t)n * 32 + c8;
#pragma unroll
  for (int k = 0; k < 8; ++k) __builtin_nontemporal_store(a[k], p + k);
}

// ------- combine2 + classifier v3: thread-per-node, weights in LDS
//         (float4 broadcast reads), data in registers, one barrier ---------
__global__ __launch_bounds__(BLK) void k_combine2cls(
    const float* __restrict__ aggT, const float* __restrict__ aggI,
    const unsigned short* __restrict__ h1b, const int* __restrict__ degT,
    const int* __restrict__ degI, const float* __restrict__ Wt,
    const float* __restrict__ bt, const float* __restrict__ Wi,
    const float* __restrict__ bi, const float* __restrict__ Wr,
    const float* __restrict__ br, const float* __restrict__ Wc,
    const float* __restrict__ bc, float* __restrict__ out, int N) {
  __shared__ float sWt[1024], sWi[1024], sWr[1024];
  __shared__ float sWc[224], sbc[7], sb[96];
  int t = threadIdx.x;
  for (int i = t; i < 1024; i += BLK) {
    sWt[i] = Wt[i];
    sWi[i] = Wi[i];
    sWr[i] = Wr[i];
  }
  if (t < 224) sWc[t] = Wc[t];
  if (t < 7) sbc[t] = bc[t];
  if (t < 32) { sb[t] = bt[t]; sb[32 + t] = bi[t]; sb[64 + t] = br[t]; }
  __syncthreads();
  int n = blockIdx.x * BLK + t;
  if (n >= N) return;
  float dT = (float)degT[n], dI = (float)degI[n];
  float invI = 1.0f / fmaxf(dI, 1.0f);
  float gate = (dI > 0.0f) ? 1.0f : 0.0f;
  float acc[32], cur[32];
#pragma unroll
  for (int j = 0; j < 32; ++j)
    acc[j] = dT * sb[j] + gate * sb[32 + j] + sb[64 + j];
  // aggT @ Wt
  {
    const float4* p4 = (const float4*)(aggT + (size_t)n * 32);
#pragma unroll
    for (int q = 0; q < 8; ++q) {
      float4 v = p4[q];
      cur[q * 4 + 0] = v.x; cur[q * 4 + 1] = v.y;
      cur[q * 4 + 2] = v.z; cur[q * 4 + 3] = v.w;
    }
#pragma unroll
    for (int k = 0; k < 32; ++k) {
      float av = cur[k];
      const float4* w4 = (const float4*)(sWt + k * 32);
#pragma unroll
      for (int q = 0; q < 8; ++q) {
        float4 w = w4[q];
        acc[q * 4 + 0] += av * w.x; acc[q * 4 + 1] += av * w.y;
        acc[q * 4 + 2] += av * w.z; acc[q * 4 + 3] += av * w.w;
      }
    }
  }
  // (aggI * invI) @ Wi
  {
    const float4* p4 = (const float4*)(aggI + (size_t)n * 32);
#pragma unroll
    for (int q = 0; q < 8; ++q) {
      float4 v = p4[q];
      cur[q * 4 + 0] = v.x * invI; cur[q * 4 + 1] = v.y * invI;
      cur[q * 4 + 2] = v.z * invI; cur[q * 4 + 3] = v.w * invI;
    }
#pragma unroll
    for (int k = 0; k < 32; ++k) {
      float av = cur[k];
      const float4* w4 = (const float4*)(sWi + k * 32);
#pragma unroll
      for (int q = 0; q < 8; ++q) {
        float4 w = w4[q];
        acc[q * 4 + 0] += av * w.x; acc[q * 4 + 1] += av * w.y;
        acc[q * 4 + 2] += av * w.z; acc[q * 4 + 3] += av * w.w;
      }
    }
  }
  // h1 residual @ Wr
  {
    const us8* p8 = (const us8*)(h1b + (size_t)n * 32);
#pragma unroll
    for (int q = 0; q < 4; ++q) {
      us8 v = p8[q];
#pragma unroll
      for (int k = 0; k < 8; ++k) cur[q * 8 + k] = bf2f(v[k]);
    }
#pragma unroll
    for (int k = 0; k < 32; ++k) {
      float av = cur[k];
      const float4* w4 = (const float4*)(sWr + k * 32);
#pragma unroll
      for (int q = 0; q < 8; ++q) {
        float4 w = w4[q];
        acc[q * 4 + 0] += av * w.x; acc[q * 4 + 1] += av * w.y;
        acc[q * 4 + 2] += av * w.z; acc[q * 4 + 3] += av * w.w;
      }
    }
  }
  // ReLU + classifier
  float o[7];
#pragma unroll
  for (int c = 0; c < 7; ++c) o[c] = sbc[c];
#pragma unroll
  for (int k = 0; k < 32; ++k) {
    float hv = fmaxf(acc[k], 0.0f);
#pragma unroll
    for (int c = 0; c < 7; ++c) o[c] += hv * sWc[k * 7 + c];
  }
  float* po = out + (size_t)n * 7;
#pragma unroll
  for (int c = 0; c < 7; ++c) po[c] = o[c];
}

extern "C" void kernel_launch(void* const* d_in, const int* in_sizes, int n_in,
                              void* d_out, int out_size, void* d_ws,
                              size_t ws_size, hipStream_t stream) {
  const float* x   = (const float*)d_in[0];
  const int* ei_t  = (const int*)d_in[1];
  const int* ei_i  = (const int*)d_in[2];
  const float* W1t = (const float*)d_in[3];
  const float* b1t = (const float*)d_in[4];
  const float* W1i = (const float*)d_in[5];
  const float* b1i = (const float*)d_in[6];
  const float* W1r = (const float*)d_in[7];
  const float* b1r = (const float*)d_in[8];
  const float* W2t = (const float*)d_in[9];
  const float* b2t = (const float*)d_in[10];
  const float* W2i = (const float*)d_in[11];
  const float* b2i = (const float*)d_in[12];
  const float* W2r = (const float*)d_in[13];
  const float* b2r = (const float*)d_in[14];
  const float* Wc  = (const float*)d_in[15];
  const float* bc  = (const float*)d_in[16];
  float* out = (float*)d_out;

  const int N  = in_sizes[0] / 6;
  const int E  = in_sizes[1] / 2;
  const int Ei = in_sizes[2] / 2;
  const int K  = (N + RN - 1) / RN;
  const int halfN = N >> 1;   // halves must fit ushort: N <= 131070

  float* aggT = (float*)d_ws;
  float* aggI = aggT + (size_t)N * 32;
  unsigned short* h1b = (unsigned short*)(aggI + (size_t)N * 32);
  unsigned short* xp  = h1b + (size_t)N * 32;
  int* curT   = (int*)(xp + (size_t)N * 8);
  int* curI   = curT + KMAX;
  int* startT = curI + KMAX;
  int* degT   = startT + N;
  int* midT   = degT + N;
  int* startI = midT + N;
  int* degI   = startI + N;
  int* midI   = degI + N;
  int* binT   = midI + N;
  int* binI   = binT + (size_t)K * CAP;
  unsigned short* csrT = (unsigned short*)(binI + (size_t)K * CAP);
  unsigned short* csrI = csrT + (size_t)K * CAP;

  const int gN8  = (N * 8 + BLK - 1) / BLK;
  const int gG1  = (N + GN1 - 1) / GN1;
  const int gG2  = (N * 4 + BLK - 1) / BLK;
  const int gC2  = (N + BLK - 1) / BLK;
  const int Emax = (E > Ei) ? E : Ei;
  const int gBin = (Emax + CHUNK - 1) / CHUNK;

  // ---- build ----
  k_prep<<<gN8, BLK, 0, stream>>>(x, xp, curT, curI, N, K);
  k_bin3<<<dim3(gBin, 2), BLK, 0, stream>>>(ei_t, E, curT, binT, ei_i, Ei,
                                            curI, binI, K);
  k_sortcsr2m<<<dim3(K, 2), 512, 0, stream>>>(binT, curT, csrT, startT, degT,
                                              midT, binI, curI, csrI, startI,
                                              degI, midI, N, halfN);

  // ---- Layer 1 (fused gather+transform -> bf16 h1, 16B row loads) ----
  k_g1c1<<<gG1, BLK, 0, stream>>>(xp, x, startT, degT, midT, csrT, startI,
                                  degI, midI, csrI, W1t, b1t, W1i, b1i, W1r,
                                  b1r, h1b, N, halfN);

  // ---- Layer 2 (src-half phased gather, then combine v3 + cls) ----
  k_gather2<<<dim3(gG2, 2), BLK, 0, stream>>>(h1b, startT, degT, midT, csrT,
                                              startI, degI, midI, csrI, aggT,
                                              aggI, N, halfN);
  k_combine2cls<<<gC2, BLK, 0, stream>>>(aggT, aggI, h1b, degT, degI, W2t,
                                         b2t, W2i, b2i, W2r, b2r, Wc, bc, out,
                                         N);
}

// Round 10
// 244.765 us; speedup vs baseline: 1.2888x; 1.0285x over previous
//
#include <hip/hip_runtime.h>

// Round 29: r26 config (best, 251.4us; combine reverted to r26's r17-style
// after v2/v3 spill fiascos) with TWO scattered-request eliminations in the
// build/L1 block (the ~125us budget holder), different kernels so rocprof
// disambiguates:
//  - k_sortcsr2m: scatter pass now writes into a 22.5KB LDS buffer (pos <
//    CAP always), then streams out coalesced as u32. Removes ~4M scattered
//    2B global writes.
//  - k_g1c1: block's 32 nodes are bucket-contiguous -> each etype's csr
//    segment is one contiguous run; stage it into LDS cooperatively
//    (coalesced), threads read indices from LDS. Cap 2048/etype, global
//    fallback if exceeded.
//
// ws: aggT[N*32] aggI[N*32] f32 | h1b[N*32] xp[N*8] bf16 | curT curI |
//     startT degT midT startI degI midI [N] | binT binI [K*CAP] int |
//     csrT csrI [K*CAP] ushort

#define BLK 256
#define RN 512            // nodes per bucket
#define KMAX 256          // max buckets (N <= 131072)
#define CAP 11264         // bucket capacity (mean 10204, +10 sigma)
#define CHUNK 4096        // edges per bin3 block
#define CSRC 2048         // per-etype LDS csr cap in g1c1

typedef unsigned short us8 __attribute__((ext_vector_type(8)));

__device__ inline unsigned short f2bf(float f) {
  unsigned u = __float_as_uint(f);
  return (unsigned short)((u + 0x7FFFu + ((u >> 16) & 1u)) >> 16);
}
__device__ inline float bf2f(unsigned short h) {
  return __uint_as_float(((unsigned)h) << 16);
}

// ---------------- prep: x -> bf16 padded rows; init bucket cursors ----------
__global__ __launch_bounds__(BLK) void k_prep(const float* __restrict__ x,
                                              unsigned short* __restrict__ xp,
                                              int* __restrict__ curT,
                                              int* __restrict__ curI, int N,
                                              int K) {
  int gid = blockIdx.x * BLK + threadIdx.x;
  if (gid < K) {
    curT[gid] = gid * CAP;
    curI[gid] = gid * CAP;
  }
  if (gid >= N * 8) return;
  int n = gid >> 3, c = gid & 7;
  xp[gid] = (c < 6) ? f2bf(x[n * 6 + c]) : (unsigned short)0;
}

// ---------------- bin: LDS-staged local sort, coalesced run writes ----------
__global__ __launch_bounds__(BLK) void k_bin3(
    const int* __restrict__ eiT, int ET, int* __restrict__ curT,
    int* __restrict__ binT, const int* __restrict__ eiI, int EI,
    int* __restrict__ curI, int* __restrict__ binI, int K) {
  const int* ei = blockIdx.y ? eiI : eiT;
  int E = blockIdx.y ? EI : ET;
  int* gcur = blockIdx.y ? curI : curT;
  int* binned = blockIdx.y ? binI : binT;
  int cs = blockIdx.x * CHUNK;
  if (cs >= E) return;
  int ce = min(E, cs + CHUNK);
  int cnt = ce - cs;
  __shared__ int ebuf[CHUNK];
  __shared__ unsigned char bbuf[CHUNK];
  __shared__ int hist[KMAX], cur[KMAX], gdelta[KMAX], s[KMAX];
  int t = threadIdx.x;
  hist[t] = 0;
  __syncthreads();
  for (int e = cs + t; e < ce; e += BLK) atomicAdd(&hist[ei[E + e] >> 9], 1);
  __syncthreads();
  int v = hist[t];
  s[t] = v;
  __syncthreads();
  for (int off = 1; off < KMAX; off <<= 1) {
    int x = (t >= off) ? s[t - off] : 0;
    __syncthreads();
    s[t] += x;
    __syncthreads();
  }
  int excl = s[t] - v;
  cur[t] = excl;
  if (t < K) gdelta[t] = atomicAdd(&gcur[t], v) - excl;
  __syncthreads();
  for (int e = cs + t; e < ce; e += BLK) {
    int src = ei[e];
    int d = ei[E + e];
    int b = d >> 9;
    int slot = atomicAdd(&cur[b], 1);
    ebuf[slot] = (src << 9) | (d & 511);
    bbuf[slot] = (unsigned char)b;
  }
  __syncthreads();
  for (int i = t; i < cnt; i += BLK) {
    int b = bbuf[i];
    __builtin_nontemporal_store(ebuf[i], &binned[i + gdelta[b]]);
  }
}

// per-bucket counting sort, (node, src-half) keys -> 16-bit csr + start/deg/mid
// scatter goes into LDS (pos < CAP), then coalesced u32 write-out.
__global__ __launch_bounds__(512) void k_sortcsr2m(
    const int* __restrict__ binT, const int* __restrict__ curT,
    unsigned short* __restrict__ csrT, int* __restrict__ startT,
    int* __restrict__ degT, int* __restrict__ midT,
    const int* __restrict__ binI, const int* __restrict__ curI,
    unsigned short* __restrict__ csrI, int* __restrict__ startI,
    int* __restrict__ degI, int* __restrict__ midI, int N, int halfN) {
  const int* bin = blockIdx.y ? binI : binT;
  const int* cur = blockIdx.y ? curI : curT;
  unsigned short* csr = blockIdx.y ? csrI : csrT;
  int* start = blockIdx.y ? startI : startT;
  int* deg = blockIdx.y ? degI : degT;
  int* mid = blockIdx.y ? midI : midT;
  __shared__ int h[2 * RN], s[RN], c2[2 * RN];
  __shared__ unsigned short lcsr[CAP];
  int t = threadIdx.x, b = blockIdx.x;
  int e0 = b * CAP;
  int cnt = min(cur[b] - e0, CAP);
  h[t] = 0;
  h[t + RN] = 0;
  __syncthreads();
  for (int i = t; i < cnt; i += 512) {
    int p = bin[e0 + i];
    int key = ((p & 511) << 1) | ((p >> 9) >= halfN ? 1 : 0);
    atomicAdd(&h[key], 1);
  }
  __syncthreads();
  int lo = h[2 * t], hi = h[2 * t + 1];
  int pair = lo + hi;
  s[t] = pair;
  __syncthreads();
  for (int off = 1; off < 512; off <<= 1) {
    int v = (t >= off) ? s[t - off] : 0;
    __syncthreads();
    s[t] += v;
    __syncthreads();
  }
  int excl = s[t] - pair;
  c2[2 * t] = excl;
  c2[2 * t + 1] = excl + lo;
  int n = b * RN + t;
  if (n < N) {
    start[n] = e0 + excl;
    deg[n] = pair;
    mid[n] = e0 + excl + lo;
  }
  __syncthreads();
  for (int i = t; i < cnt; i += 512) {
    int p = bin[e0 + i];
    int src = p >> 9;
    int hiFlag = (src >= halfN) ? 1 : 0;
    int key = ((p & 511) << 1) | hiFlag;
    int pos = atomicAdd(&c2[key], 1);
    lcsr[pos] = (unsigned short)(src - hiFlag * halfN);
  }
  __syncthreads();
  // coalesced write-out (e0*2 bytes is 4B-aligned since CAP is even)
  unsigned int* dst = (unsigned int*)(csr + e0);
  const unsigned int* srcp = (const unsigned int*)lcsr;
  int cnt2 = cnt >> 1;
  for (int i = t; i < cnt2; i += 512) dst[i] = srcp[i];
  if (t == 0 && (cnt & 1)) csr[e0 + cnt - 1] = lcsr[cnt - 1];
}

// ------- fused layer 1: 8 thr/node (etype x src-half x edge-parity),
//         LDS-staged csr segments, full 16B row loads ----------
#define GN1 32
__global__ __launch_bounds__(BLK) void k_g1c1(
    const unsigned short* __restrict__ xp, const float* __restrict__ x,
    const int* __restrict__ startT, const int* __restrict__ degT,
    const int* __restrict__ midT, const unsigned short* __restrict__ csrT,
    const int* __restrict__ startI, const int* __restrict__ degI,
    const int* __restrict__ midI, const unsigned short* __restrict__ csrI,
    const float* __restrict__ Wt, const float* __restrict__ bt,
    const float* __restrict__ Wi, const float* __restrict__ bi,
    const float* __restrict__ Wr, const float* __restrict__ br,
    unsigned short* __restrict__ h1b, int N, int halfN) {
  __shared__ float sGT[GN1 * 32], sGI[GN1 * 32], sx[GN1 * 6];
  __shared__ float sWt[192], sWi[192], sWr[192], sb[96];
  __shared__ float sdT[GN1], sdI[GN1];
  __shared__ unsigned short lcT[CSRC], lcI[CSRC];
  __shared__ int sm[4];
  int t = threadIdx.x, b = blockIdx.x;
  if (t < 192) { sWt[t] = Wt[t]; sWi[t] = Wi[t]; sWr[t] = Wr[t]; }
  if (t < 32) { sb[t] = bt[t]; sb[32 + t] = bi[t]; sb[64 + t] = br[t]; }
  if (t < GN1 * 6) {
    int g = b * GN1 * 6 + t;
    sx[t] = (g < N * 6) ? x[g] : 0.0f;
  }
  int n0 = b * GN1;
  if (t == 0) {
    // block's 32 nodes are bucket-contiguous: csr segment per etype is one
    // contiguous run [start[n0], start[nL]+deg[nL])
    int nL = min(n0 + GN1, N) - 1;
    int bT = startT[n0];
    sm[0] = bT;
    sm[1] = startT[nL] + degT[nL] - bT;
    int bI = startI[n0];
    sm[2] = bI;
    sm[3] = startI[nL] + degI[nL] - bI;
  }
  __syncthreads();
  int baseT = sm[0], lenT = sm[1], baseI = sm[2], lenI = sm[3];
  {
    int lt = min(lenT, CSRC);
    for (int i = t; i < lt; i += BLK) lcT[i] = csrT[baseT + i];
    int li = min(lenI, CSRC);
    for (int i = t; i < li; i += BLK) lcI[i] = csrI[baseI + i];
  }
  __syncthreads();
  int nl = t >> 3, et = (t >> 2) & 1, half = (t >> 1) & 1, par = t & 1;
  int n = n0 + nl;
  float a[8] = {0.f, 0.f, 0.f, 0.f, 0.f, 0.f, 0.f, 0.f};
  int d = 0;
  if (n < N) {
    const int* startA = et ? startI : startT;
    const int* degA = et ? degI : degT;
    const int* midA = et ? midI : midT;
    int baseA = et ? baseI : baseT;
    int lenA = et ? lenI : lenT;
    const unsigned short* csrp =
        (lenA <= CSRC) ? (const unsigned short*)(et ? lcI : lcT)
                       : ((et ? csrI : csrT) + baseA);
    int s0 = startA[n];
    d = degA[n];
    int m = midA[n];
    int i0 = (half ? m : s0) - baseA;
    int i1 = (half ? (s0 + d) : m) - baseA;
    const unsigned short* tab = xp + (half ? (size_t)halfN * 8 : 0);
    int i = i0 + par;
    for (; i + 6 < i1; i += 8) {
      int r0 = csrp[i], r1 = csrp[i + 2], r2 = csrp[i + 4], r3 = csrp[i + 6];
      us8 v0 = *(const us8*)(tab + (size_t)r0 * 8);
      us8 v1 = *(const us8*)(tab + (size_t)r1 * 8);
      us8 v2 = *(const us8*)(tab + (size_t)r2 * 8);
      us8 v3 = *(const us8*)(tab + (size_t)r3 * 8);
#pragma unroll
      for (int k = 0; k < 8; ++k)
        a[k] += (bf2f(v0[k]) + bf2f(v1[k])) + (bf2f(v2[k]) + bf2f(v3[k]));
    }
    for (; i < i1; i += 2) {
      int r0 = csrp[i];
      us8 v0 = *(const us8*)(tab + (size_t)r0 * 8);
#pragma unroll
      for (int k = 0; k < 8; ++k) a[k] += bf2f(v0[k]);
    }
  }
  // slot = half*2 + par; 4 slots x 8ch = 32 floats per (node, etype)
  float* dst = (et ? sGI : sGT) + nl * 32 + (half * 2 + par) * 8;
#pragma unroll
  for (int k = 0; k < 8; ++k) dst[k] = a[k];
  if (half == 0 && par == 0) {
    if (et) sdI[nl] = (float)d;
    else    sdT[nl] = (float)d;
  }
  __syncthreads();
  for (int idx = t; idx < GN1 * 32; idx += BLK) {
    int m = idx >> 5, j = idx & 31;
    int nn = n0 + m;
    if (nn >= N) break;
    float fdT = sdT[m], fdI = sdI[m];
    float invI = 1.0f / fmaxf(fdI, 1.0f);
    float gate = (fdI > 0.0f) ? 1.0f : 0.0f;
    float acc = fdT * sb[j] + gate * sb[32 + j] + sb[64 + j];
#pragma unroll
    for (int k = 0; k < 6; ++k) {
      float gT = sGT[m * 32 + k] + sGT[m * 32 + 8 + k] +
                 sGT[m * 32 + 16 + k] + sGT[m * 32 + 24 + k];
      float gI = sGI[m * 32 + k] + sGI[m * 32 + 8 + k] +
                 sGI[m * 32 + 16 + k] + sGI[m * 32 + 24 + k];
      acc += gT * sWt[k * 32 + j];
      acc += gI * invI * sWi[k * 32 + j];
      acc += sx[m * 6 + k] * sWr[k * 32 + j];
    }
    h1b[(size_t)nn * 32 + j] = f2bf(fmaxf(acc, 0.0f));
  }
}

// ---------------- layer-2 gather helper: unroll-4, 16B bf16 loads ----------
__device__ inline void accum8(const unsigned short* __restrict__ tab,
                              const unsigned short* __restrict__ csr, int i0,
                              int i1, float* a) {
  int i = i0;
  for (; i + 4 <= i1; i += 4) {
    int r0 = csr[i], r1 = csr[i + 1], r2 = csr[i + 2], r3 = csr[i + 3];
    us8 v0 = *(const us8*)(tab + (size_t)r0 * 32);
    us8 v1 = *(const us8*)(tab + (size_t)r1 * 32);
    us8 v2 = *(const us8*)(tab + (size_t)r2 * 32);
    us8 v3 = *(const us8*)(tab + (size_t)r3 * 32);
#pragma unroll
    for (int k = 0; k < 8; ++k)
      a[k] += (bf2f(v0[k]) + bf2f(v1[k])) + (bf2f(v2[k]) + bf2f(v3[k]));
  }
  for (; i < i1; ++i) {
    int r0 = csr[i];
    us8 v0 = *(const us8*)(tab + (size_t)r0 * 32);
#pragma unroll
    for (int k = 0; k < 8; ++k) a[k] += bf2f(v0[k]);
  }
}

// --- layer-2 gather: 4 thr/node (chan-quarter), src-half phased (r19) ------
__global__ __launch_bounds__(BLK) void k_gather2(
    const unsigned short* __restrict__ h1b, const int* __restrict__ startT,
    const int* __restrict__ degT, const int* __restrict__ midT,
    const unsigned short* __restrict__ csrT, const int* __restrict__ startI,
    const int* __restrict__ degI, const int* __restrict__ midI,
    const unsigned short* __restrict__ csrI, float* __restrict__ aggT,
    float* __restrict__ aggI, int N, int halfN) {
  const int* start = blockIdx.y ? startI : startT;
  const int* deg = blockIdx.y ? degI : degT;
  const int* mid = blockIdx.y ? midI : midT;
  const unsigned short* csr = blockIdx.y ? csrI : csrT;
  float* agg = blockIdx.y ? aggI : aggT;
  int gid = blockIdx.x * BLK + threadIdx.x;
  int n = gid >> 2;
  if (n >= N) return;
  int c8 = (gid & 3) * 8;
  float a[8] = {0.f, 0.f, 0.f, 0.f, 0.f, 0.f, 0.f, 0.f};
  int s0 = start[n], d = deg[n], m = mid[n];
  // phase 0: src < N/2 (lower table half L2-resident chip-wide), then phase 1
  accum8(h1b + c8, csr, s0, m, a);
  accum8(h1b + (size_t)halfN * 32 + c8, csr, m, s0 + d, a);
  float* p = agg + (size_t)n * 32 + c8;
#pragma unroll
  for (int k = 0; k < 8; ++k) __builtin_nontemporal_store(a[k], p + k);
}

// ------- combine2 + classifier: one-barrier full staging, reg weights ------
#define CN 64
__global__ __launch_bounds__(BLK) void k_combine2cls(
    const float* __restrict__ aggT, const float* __restrict__ aggI,
    const unsigned short* __restrict__ h1b, const int* __restrict__ degT,
    const int* __restrict__ degI, const float* __restrict__ Wt,
    const float* __restrict__ bt, const float* __restrict__ Wi,
    const float* __restrict__ bi, const float* __restrict__ Wr,
    const float* __restrict__ br, const float* __restrict__ Wc,
    const float* __restrict__ bc, float* __restrict__ out, int N) {
  __shared__ float hTs[CN * 32], hIs[CN * 32], hRs[CN * 32], hs2[CN * 32];
  __shared__ float sWc[224], sbc[7], sb[96];
  __shared__ float sdT[CN], sdI[CN];
  int t = threadIdx.x;
  int j = t & 31, ln = t >> 5;
  float wt[32], wi[32], wr[32];
#pragma unroll
  for (int k = 0; k < 32; ++k) {
    wt[k] = Wt[k * 32 + j];
    wi[k] = Wi[k * 32 + j];
    wr[k] = Wr[k * 32 + j];
  }
  int node0 = blockIdx.x * CN;
  size_t gbase = (size_t)node0 * 32;
  {
    const float4* sT = (const float4*)(aggT + gbase);
    const float4* sI = (const float4*)(aggI + gbase);
    ((float4*)hTs)[t] = sT[t];
    ((float4*)hTs)[t + 256] = sT[t + 256];
    ((float4*)hIs)[t] = sI[t];
    ((float4*)hIs)[t + 256] = sI[t + 256];
    us8 v = ((const us8*)(h1b + gbase))[t];
    float4 lo = {bf2f(v[0]), bf2f(v[1]), bf2f(v[2]), bf2f(v[3])};
    float4 hi = {bf2f(v[4]), bf2f(v[5]), bf2f(v[6]), bf2f(v[7])};
    ((float4*)hRs)[2 * t] = lo;
    ((float4*)hRs)[2 * t + 1] = hi;
  }
  if (t < 224) sWc[t] = Wc[t];
  if (t < 7) sbc[t] = bc[t];
  if (t < 32) { sb[t] = bt[t]; sb[32 + t] = bi[t]; sb[64 + t] = br[t]; }
  if (t < CN) {
    int n = node0 + t;
    sdT[t] = (n < N) ? (float)degT[n] : 0.f;
    sdI[t] = (n < N) ? (float)degI[n] : 0.f;
  }
  __syncthreads();
#pragma unroll
  for (int it = 0; it < CN / 8; ++it) {
    int li = it * 8 + ln;
    float dT = sdT[li], dI = sdI[li];
    float invI = 1.0f / fmaxf(dI, 1.0f);
    float gate = (dI > 0.0f) ? 1.0f : 0.0f;
    float aT = 0.f, aI = 0.f, aR = 0.f;
    const float4* hT4 = (const float4*)(hTs + li * 32);
    const float4* hI4 = (const float4*)(hIs + li * 32);
    const float4* hR4 = (const float4*)(hRs + li * 32);
#pragma unroll
    for (int kk = 0; kk < 8; ++kk) {
      float4 a = hT4[kk], bI = hI4[kk], r = hR4[kk];
      aT += a.x * wt[kk * 4 + 0] + a.y * wt[kk * 4 + 1] +
            a.z * wt[kk * 4 + 2] + a.w * wt[kk * 4 + 3];
      aI += bI.x * wi[kk * 4 + 0] + bI.y * wi[kk * 4 + 1] +
            bI.z * wi[kk * 4 + 2] + bI.w * wi[kk * 4 + 3];
      aR += r.x * wr[kk * 4 + 0] + r.y * wr[kk * 4 + 1] +
            r.z * wr[kk * 4 + 2] + r.w * wr[kk * 4 + 3];
    }
    float acc = dT * sb[j] + gate * sb[32 + j] + sb[64 + j] + aT + invI * aI + aR;
    hs2[li * 32 + j] = fmaxf(acc, 0.0f);
  }
  __syncthreads();
  if (t < 224) {
#pragma unroll
    for (int pass = 0; pass < CN * 7 / 224; ++pass) {
      int o = pass * 224 + t;
      int m = o / 7, jc = o - m * 7;
      int n = node0 + m;
      if (n < N) {
        float a = sbc[jc];
        const float* hp = hs2 + m * 32;
#pragma unroll
        for (int k = 0; k < 32; ++k) a += hp[k] * sWc[k * 7 + jc];
        out[(size_t)n * 7 + jc] = a;
      }
    }
  }
}

extern "C" void kernel_launch(void* const* d_in, const int* in_sizes, int n_in,
                              void* d_out, int out_size, void* d_ws,
                              size_t ws_size, hipStream_t stream) {
  const float* x   = (const float*)d_in[0];
  const int* ei_t  = (const int*)d_in[1];
  const int* ei_i  = (const int*)d_in[2];
  const float* W1t = (const float*)d_in[3];
  const float* b1t = (const float*)d_in[4];
  const float* W1i = (const float*)d_in[5];
  const float* b1i = (const float*)d_in[6];
  const float* W1r = (const float*)d_in[7];
  const float* b1r = (const float*)d_in[8];
  const float* W2t = (const float*)d_in[9];
  const float* b2t = (const float*)d_in[10];
  const float* W2i = (const float*)d_in[11];
  const float* b2i = (const float*)d_in[12];
  const float* W2r = (const float*)d_in[13];
  const float* b2r = (const float*)d_in[14];
  const float* Wc  = (const float*)d_in[15];
  const float* bc  = (const float*)d_in[16];
  float* out = (float*)d_out;

  const int N  = in_sizes[0] / 6;
  const int E  = in_sizes[1] / 2;
  const int Ei = in_sizes[2] / 2;
  const int K  = (N + RN - 1) / RN;
  const int halfN = N >> 1;   // halves must fit ushort: N <= 131070

  float* aggT = (float*)d_ws;
  float* aggI = aggT + (size_t)N * 32;
  unsigned short* h1b = (unsigned short*)(aggI + (size_t)N * 32);
  unsigned short* xp  = h1b + (size_t)N * 32;
  int* curT   = (int*)(xp + (size_t)N * 8);
  int* curI   = curT + KMAX;
  int* startT = curI + KMAX;
  int* degT   = startT + N;
  int* midT   = degT + N;
  int* startI = midT + N;
  int* degI   = startI + N;
  int* midI   = degI + N;
  int* binT   = midI + N;
  int* binI   = binT + (size_t)K * CAP;
  unsigned short* csrT = (unsigned short*)(binI + (size_t)K * CAP);
  unsigned short* csrI = csrT + (size_t)K * CAP;

  const int gN8  = (N * 8 + BLK - 1) / BLK;
  const int gG1  = (N + GN1 - 1) / GN1;
  const int gG2  = (N * 4 + BLK - 1) / BLK;
  const int gC2  = (N + CN - 1) / CN;
  const int Emax = (E > Ei) ? E : Ei;
  const int gBin = (Emax + CHUNK - 1) / CHUNK;

  // ---- build ----
  k_prep<<<gN8, BLK, 0, stream>>>(x, xp, curT, curI, N, K);
  k_bin3<<<dim3(gBin, 2), BLK, 0, stream>>>(ei_t, E, curT, binT, ei_i, Ei,
                                            curI, binI, K);
  k_sortcsr2m<<<dim3(K, 2), 512, 0, stream>>>(binT, curT, csrT, startT, degT,
                                              midT, binI, curI, csrI, startI,
                                              degI, midI, N, halfN);

  // ---- Layer 1 (fused gather+transform -> bf16 h1, LDS csr staging) ----
  k_g1c1<<<gG1, BLK, 0, stream>>>(xp, x, startT, degT, midT, csrT, startI,
                                  degI, midI, csrI, W1t, b1t, W1i, b1i, W1r,
                                  b1r, h1b, N, halfN);

  // ---- Layer 2 (src-half phased gather, then combine+cls) ----
  k_gather2<<<dim3(gG2, 2), BLK, 0, stream>>>(h1b, startT, degT, midT, csrT,
                                              startI, degI, midI, csrI, aggT,
                                              aggI, N, halfN);
  k_combine2cls<<<gC2, BLK, 0, stream>>>(aggT, aggI, h1b, degT, degI, W2t,
                                         b2t, W2i, b2i, W2r, b2r, Wc, bc, out,
                                         N);
}

// Round 11
// 238.411 us; speedup vs baseline: 1.3231x; 1.0267x over previous
//
#include <hip/hip_runtime.h>

// Round 30: r29 config verbatim (measured best 244.8us) with ONE change:
// k_bin3 caches its 16 (src,dst) edge pairs in statically-indexed registers
// across the scan, eliminating the second global read of the edge list
// (pass 2 previously re-read ei[e] and ei[E+e]: 32MB + latency). Same
// proven lever as r26/r29: scattered/redundant VMEM request elimination.
// No layout, sync, or occupancy changes.
//
// ws: aggT[N*32] aggI[N*32] f32 | h1b[N*32] xp[N*8] bf16 | curT curI |
//     startT degT midT startI degI midI [N] | binT binI [K*CAP] int |
//     csrT csrI [K*CAP] ushort

#define BLK 256
#define RN 512            // nodes per bucket
#define KMAX 256          // max buckets (N <= 131072)
#define CAP 11264         // bucket capacity (mean 10204, +10 sigma)
#define CHUNK 4096        // edges per bin3 block
#define EPT 16            // edges per thread in bin3 (CHUNK/BLK)
#define CSRC 2048         // per-etype LDS csr cap in g1c1

typedef unsigned short us8 __attribute__((ext_vector_type(8)));

__device__ inline unsigned short f2bf(float f) {
  unsigned u = __float_as_uint(f);
  return (unsigned short)((u + 0x7FFFu + ((u >> 16) & 1u)) >> 16);
}
__device__ inline float bf2f(unsigned short h) {
  return __uint_as_float(((unsigned)h) << 16);
}

// ---------------- prep: x -> bf16 padded rows; init bucket cursors ----------
__global__ __launch_bounds__(BLK) void k_prep(const float* __restrict__ x,
                                              unsigned short* __restrict__ xp,
                                              int* __restrict__ curT,
                                              int* __restrict__ curI, int N,
                                              int K) {
  int gid = blockIdx.x * BLK + threadIdx.x;
  if (gid < K) {
    curT[gid] = gid * CAP;
    curI[gid] = gid * CAP;
  }
  if (gid >= N * 8) return;
  int n = gid >> 3, c = gid & 7;
  xp[gid] = (c < 6) ? f2bf(x[n * 6 + c]) : (unsigned short)0;
}

// ---------------- bin: LDS-staged local sort, register-cached edges --------
__global__ __launch_bounds__(BLK) void k_bin3(
    const int* __restrict__ eiT, int ET, int* __restrict__ curT,
    int* __restrict__ binT, const int* __restrict__ eiI, int EI,
    int* __restrict__ curI, int* __restrict__ binI, int K) {
  const int* ei = blockIdx.y ? eiI : eiT;
  int E = blockIdx.y ? EI : ET;
  int* gcur = blockIdx.y ? curI : curT;
  int* binned = blockIdx.y ? binI : binT;
  int cs = blockIdx.x * CHUNK;
  if (cs >= E) return;
  int ce = min(E, cs + CHUNK);
  int cnt = ce - cs;
  __shared__ int ebuf[CHUNK];
  __shared__ unsigned char bbuf[CHUNK];
  __shared__ int hist[KMAX], cur[KMAX], gdelta[KMAX], s[KMAX];
  int t = threadIdx.x;
  hist[t] = 0;
  __syncthreads();
  int rs[EPT], rd[EPT];
#pragma unroll
  for (int i = 0; i < EPT; ++i) {
    int e = cs + t + i * BLK;
    if (e < ce) {
      rs[i] = ei[e];
      rd[i] = ei[E + e];
      atomicAdd(&hist[rd[i] >> 9], 1);
    }
  }
  __syncthreads();
  int v = hist[t];
  s[t] = v;
  __syncthreads();
  for (int off = 1; off < KMAX; off <<= 1) {
    int x = (t >= off) ? s[t - off] : 0;
    __syncthreads();
    s[t] += x;
    __syncthreads();
  }
  int excl = s[t] - v;
  cur[t] = excl;
  if (t < K) gdelta[t] = atomicAdd(&gcur[t], v) - excl;
  __syncthreads();
#pragma unroll
  for (int i = 0; i < EPT; ++i) {
    int e = cs + t + i * BLK;
    if (e < ce) {
      int src = rs[i];
      int d = rd[i];
      int b = d >> 9;
      int slot = atomicAdd(&cur[b], 1);
      ebuf[slot] = (src << 9) | (d & 511);
      bbuf[slot] = (unsigned char)b;
    }
  }
  __syncthreads();
  for (int i = t; i < cnt; i += BLK) {
    int b = bbuf[i];
    __builtin_nontemporal_store(ebuf[i], &binned[i + gdelta[b]]);
  }
}

// per-bucket counting sort, (node, src-half) keys -> 16-bit csr + start/deg/mid
// scatter goes into LDS (pos < CAP), then coalesced u32 write-out.
__global__ __launch_bounds__(512) void k_sortcsr2m(
    const int* __restrict__ binT, const int* __restrict__ curT,
    unsigned short* __restrict__ csrT, int* __restrict__ startT,
    int* __restrict__ degT, int* __restrict__ midT,
    const int* __restrict__ binI, const int* __restrict__ curI,
    unsigned short* __restrict__ csrI, int* __restrict__ startI,
    int* __restrict__ degI, int* __restrict__ midI, int N, int halfN) {
  const int* bin = blockIdx.y ? binI : binT;
  const int* cur = blockIdx.y ? curI : curT;
  unsigned short* csr = blockIdx.y ? csrI : csrT;
  int* start = blockIdx.y ? startI : startT;
  int* deg = blockIdx.y ? degI : degT;
  int* mid = blockIdx.y ? midI : midT;
  __shared__ int h[2 * RN], s[RN], c2[2 * RN];
  __shared__ unsigned short lcsr[CAP];
  int t = threadIdx.x, b = blockIdx.x;
  int e0 = b * CAP;
  int cnt = min(cur[b] - e0, CAP);
  h[t] = 0;
  h[t + RN] = 0;
  __syncthreads();
  for (int i = t; i < cnt; i += 512) {
    int p = bin[e0 + i];
    int key = ((p & 511) << 1) | ((p >> 9) >= halfN ? 1 : 0);
    atomicAdd(&h[key], 1);
  }
  __syncthreads();
  int lo = h[2 * t], hi = h[2 * t + 1];
  int pair = lo + hi;
  s[t] = pair;
  __syncthreads();
  for (int off = 1; off < 512; off <<= 1) {
    int v = (t >= off) ? s[t - off] : 0;
    __syncthreads();
    s[t] += v;
    __syncthreads();
  }
  int excl = s[t] - pair;
  c2[2 * t] = excl;
  c2[2 * t + 1] = excl + lo;
  int n = b * RN + t;
  if (n < N) {
    start[n] = e0 + excl;
    deg[n] = pair;
    mid[n] = e0 + excl + lo;
  }
  __syncthreads();
  for (int i = t; i < cnt; i += 512) {
    int p = bin[e0 + i];
    int src = p >> 9;
    int hiFlag = (src >= halfN) ? 1 : 0;
    int key = ((p & 511) << 1) | hiFlag;
    int pos = atomicAdd(&c2[key], 1);
    lcsr[pos] = (unsigned short)(src - hiFlag * halfN);
  }
  __syncthreads();
  // coalesced write-out (e0*2 bytes is 4B-aligned since CAP is even)
  unsigned int* dst = (unsigned int*)(csr + e0);
  const unsigned int* srcp = (const unsigned int*)lcsr;
  int cnt2 = cnt >> 1;
  for (int i = t; i < cnt2; i += 512) dst[i] = srcp[i];
  if (t == 0 && (cnt & 1)) csr[e0 + cnt - 1] = lcsr[cnt - 1];
}

// ------- fused layer 1: 8 thr/node (etype x src-half x edge-parity),
//         LDS-staged csr segments, full 16B row loads ----------
#define GN1 32
__global__ __launch_bounds__(BLK) void k_g1c1(
    const unsigned short* __restrict__ xp, const float* __restrict__ x,
    const int* __restrict__ startT, const int* __restrict__ degT,
    const int* __restrict__ midT, const unsigned short* __restrict__ csrT,
    const int* __restrict__ startI, const int* __restrict__ degI,
    const int* __restrict__ midI, const unsigned short* __restrict__ csrI,
    const float* __restrict__ Wt, const float* __restrict__ bt,
    const float* __restrict__ Wi, const float* __restrict__ bi,
    const float* __restrict__ Wr, const float* __restrict__ br,
    unsigned short* __restrict__ h1b, int N, int halfN) {
  __shared__ float sGT[GN1 * 32], sGI[GN1 * 32], sx[GN1 * 6];
  __shared__ float sWt[192], sWi[192], sWr[192], sb[96];
  __shared__ float sdT[GN1], sdI[GN1];
  __shared__ unsigned short lcT[CSRC], lcI[CSRC];
  __shared__ int sm[4];
  int t = threadIdx.x, b = blockIdx.x;
  if (t < 192) { sWt[t] = Wt[t]; sWi[t] = Wi[t]; sWr[t] = Wr[t]; }
  if (t < 32) { sb[t] = bt[t]; sb[32 + t] = bi[t]; sb[64 + t] = br[t]; }
  if (t < GN1 * 6) {
    int g = b * GN1 * 6 + t;
    sx[t] = (g < N * 6) ? x[g] : 0.0f;
  }
  int n0 = b * GN1;
  if (t == 0) {
    // block's 32 nodes are bucket-contiguous: csr segment per etype is one
    // contiguous run [start[n0], start[nL]+deg[nL])
    int nL = min(n0 + GN1, N) - 1;
    int bT = startT[n0];
    sm[0] = bT;
    sm[1] = startT[nL] + degT[nL] - bT;
    int bI = startI[n0];
    sm[2] = bI;
    sm[3] = startI[nL] + degI[nL] - bI;
  }
  __syncthreads();
  int baseT = sm[0], lenT = sm[1], baseI = sm[2], lenI = sm[3];
  {
    int lt = min(lenT, CSRC);
    for (int i = t; i < lt; i += BLK) lcT[i] = csrT[baseT + i];
    int li = min(lenI, CSRC);
    for (int i = t; i < li; i += BLK) lcI[i] = csrI[baseI + i];
  }
  __syncthreads();
  int nl = t >> 3, et = (t >> 2) & 1, half = (t >> 1) & 1, par = t & 1;
  int n = n0 + nl;
  float a[8] = {0.f, 0.f, 0.f, 0.f, 0.f, 0.f, 0.f, 0.f};
  int d = 0;
  if (n < N) {
    const int* startA = et ? startI : startT;
    const int* degA = et ? degI : degT;
    const int* midA = et ? midI : midT;
    int baseA = et ? baseI : baseT;
    int lenA = et ? lenI : lenT;
    const unsigned short* csrp =
        (lenA <= CSRC) ? (const unsigned short*)(et ? lcI : lcT)
                       : ((et ? csrI : csrT) + baseA);
    int s0 = startA[n];
    d = degA[n];
    int m = midA[n];
    int i0 = (half ? m : s0) - baseA;
    int i1 = (half ? (s0 + d) : m) - baseA;
    const unsigned short* tab = xp + (half ? (size_t)halfN * 8 : 0);
    int i = i0 + par;
    for (; i + 6 < i1; i += 8) {
      int r0 = csrp[i], r1 = csrp[i + 2], r2 = csrp[i + 4], r3 = csrp[i + 6];
      us8 v0 = *(const us8*)(tab + (size_t)r0 * 8);
      us8 v1 = *(const us8*)(tab + (size_t)r1 * 8);
      us8 v2 = *(const us8*)(tab + (size_t)r2 * 8);
      us8 v3 = *(const us8*)(tab + (size_t)r3 * 8);
#pragma unroll
      for (int k = 0; k < 8; ++k)
        a[k] += (bf2f(v0[k]) + bf2f(v1[k])) + (bf2f(v2[k]) + bf2f(v3[k]));
    }
    for (; i < i1; i += 2) {
      int r0 = csrp[i];
      us8 v0 = *(const us8*)(tab + (size_t)r0 * 8);
#pragma unroll
      for (int k = 0; k < 8; ++k) a[k] += bf2f(v0[k]);
    }
  }
  // slot = half*2 + par; 4 slots x 8ch = 32 floats per (node, etype)
  float* dst = (et ? sGI : sGT) + nl * 32 + (half * 2 + par) * 8;
#pragma unroll
  for (int k = 0; k < 8; ++k) dst[k] = a[k];
  if (half == 0 && par == 0) {
    if (et) sdI[nl] = (float)d;
    else    sdT[nl] = (float)d;
  }
  __syncthreads();
  for (int idx = t; idx < GN1 * 32; idx += BLK) {
    int m = idx >> 5, j = idx & 31;
    int nn = n0 + m;
    if (nn >= N) break;
    float fdT = sdT[m], fdI = sdI[m];
    float invI = 1.0f / fmaxf(fdI, 1.0f);
    float gate = (fdI > 0.0f) ? 1.0f : 0.0f;
    float acc = fdT * sb[j] + gate * sb[32 + j] + sb[64 + j];
#pragma unroll
    for (int k = 0; k < 6; ++k) {
      float gT = sGT[m * 32 + k] + sGT[m * 32 + 8 + k] +
                 sGT[m * 32 + 16 + k] + sGT[m * 32 + 24 + k];
      float gI = sGI[m * 32 + k] + sGI[m * 32 + 8 + k] +
                 sGI[m * 32 + 16 + k] + sGI[m * 32 + 24 + k];
      acc += gT * sWt[k * 32 + j];
      acc += gI * invI * sWi[k * 32 + j];
      acc += sx[m * 6 + k] * sWr[k * 32 + j];
    }
    h1b[(size_t)nn * 32 + j] = f2bf(fmaxf(acc, 0.0f));
  }
}

// ---------------- layer-2 gather helper: unroll-4, 16B bf16 loads ----------
__device__ inline void accum8(const unsigned short* __restrict__ tab,
                              const unsigned short* __restrict__ csr, int i0,
                              int i1, float* a) {
  int i = i0;
  for (; i + 4 <= i1; i += 4) {
    int r0 = csr[i], r1 = csr[i + 1], r2 = csr[i + 2], r3 = csr[i + 3];
    us8 v0 = *(const us8*)(tab + (size_t)r0 * 32);
    us8 v1 = *(const us8*)(tab + (size_t)r1 * 32);
    us8 v2 = *(const us8*)(tab + (size_t)r2 * 32);
    us8 v3 = *(const us8*)(tab + (size_t)r3 * 32);
#pragma unroll
    for (int k = 0; k < 8; ++k)
      a[k] += (bf2f(v0[k]) + bf2f(v1[k])) + (bf2f(v2[k]) + bf2f(v3[k]));
  }
  for (; i < i1; ++i) {
    int r0 = csr[i];
    us8 v0 = *(const us8*)(tab + (size_t)r0 * 32);
#pragma unroll
    for (int k = 0; k < 8; ++k) a[k] += bf2f(v0[k]);
  }
}

// --- layer-2 gather: 4 thr/node (chan-quarter), src-half phased (r19) ------
__global__ __launch_bounds__(BLK) void k_gather2(
    const unsigned short* __restrict__ h1b, const int* __restrict__ startT,
    const int* __restrict__ degT, const int* __restrict__ midT,
    const unsigned short* __restrict__ csrT, const int* __restrict__ startI,
    const int* __restrict__ degI, const int* __restrict__ midI,
    const unsigned short* __restrict__ csrI, float* __restrict__ aggT,
    float* __restrict__ aggI, int N, int halfN) {
  const int* start = blockIdx.y ? startI : startT;
  const int* deg = blockIdx.y ? degI : degT;
  const int* mid = blockIdx.y ? midI : midT;
  const unsigned short* csr = blockIdx.y ? csrI : csrT;
  float* agg = blockIdx.y ? aggI : aggT;
  int gid = blockIdx.x * BLK + threadIdx.x;
  int n = gid >> 2;
  if (n >= N) return;
  int c8 = (gid & 3) * 8;
  float a[8] = {0.f, 0.f, 0.f, 0.f, 0.f, 0.f, 0.f, 0.f};
  int s0 = start[n], d = deg[n], m = mid[n];
  // phase 0: src < N/2 (lower table half L2-resident chip-wide), then phase 1
  accum8(h1b + c8, csr, s0, m, a);
  accum8(h1b + (size_t)halfN * 32 + c8, csr, m, s0 + d, a);
  float* p = agg + (size_t)n * 32 + c8;
#pragma unroll
  for (int k = 0; k < 8; ++k) __builtin_nontemporal_store(a[k], p + k);
}

// ------- combine2 + classifier: one-barrier full staging, reg weights ------
#define CN 64
__global__ __launch_bounds__(BLK) void k_combine2cls(
    const float* __restrict__ aggT, const float* __restrict__ aggI,
    const unsigned short* __restrict__ h1b, const int* __restrict__ degT,
    const int* __restrict__ degI, const float* __restrict__ Wt,
    const float* __restrict__ bt, const float* __restrict__ Wi,
    const float* __restrict__ bi, const float* __restrict__ Wr,
    const float* __restrict__ br, const float* __restrict__ Wc,
    const float* __restrict__ bc, float* __restrict__ out, int N) {
  __shared__ float hTs[CN * 32], hIs[CN * 32], hRs[CN * 32], hs2[CN * 32];
  __shared__ float sWc[224], sbc[7], sb[96];
  __shared__ float sdT[CN], sdI[CN];
  int t = threadIdx.x;
  int j = t & 31, ln = t >> 5;
  float wt[32], wi[32], wr[32];
#pragma unroll
  for (int k = 0; k < 32; ++k) {
    wt[k] = Wt[k * 32 + j];
    wi[k] = Wi[k * 32 + j];
    wr[k] = Wr[k * 32 + j];
  }
  int node0 = blockIdx.x * CN;
  size_t gbase = (size_t)node0 * 32;
  {
    const float4* sT = (const float4*)(aggT + gbase);
    const float4* sI = (const float4*)(aggI + gbase);
    ((float4*)hTs)[t] = sT[t];
    ((float4*)hTs)[t + 256] = sT[t + 256];
    ((float4*)hIs)[t] = sI[t];
    ((float4*)hIs)[t + 256] = sI[t + 256];
    us8 v = ((const us8*)(h1b + gbase))[t];
    float4 lo = {bf2f(v[0]), bf2f(v[1]), bf2f(v[2]), bf2f(v[3])};
    float4 hi = {bf2f(v[4]), bf2f(v[5]), bf2f(v[6]), bf2f(v[7])};
    ((float4*)hRs)[2 * t] = lo;
    ((float4*)hRs)[2 * t + 1] = hi;
  }
  if (t < 224) sWc[t] = Wc[t];
  if (t < 7) sbc[t] = bc[t];
  if (t < 32) { sb[t] = bt[t]; sb[32 + t] = bi[t]; sb[64 + t] = br[t]; }
  if (t < CN) {
    int n = node0 + t;
    sdT[t] = (n < N) ? (float)degT[n] : 0.f;
    sdI[t] = (n < N) ? (float)degI[n] : 0.f;
  }
  __syncthreads();
#pragma unroll
  for (int it = 0; it < CN / 8; ++it) {
    int li = it * 8 + ln;
    float dT = sdT[li], dI = sdI[li];
    float invI = 1.0f / fmaxf(dI, 1.0f);
    float gate = (dI > 0.0f) ? 1.0f : 0.0f;
    float aT = 0.f, aI = 0.f, aR = 0.f;
    const float4* hT4 = (const float4*)(hTs + li * 32);
    const float4* hI4 = (const float4*)(hIs + li * 32);
    const float4* hR4 = (const float4*)(hRs + li * 32);
#pragma unroll
    for (int kk = 0; kk < 8; ++kk) {
      float4 a = hT4[kk], bI = hI4[kk], r = hR4[kk];
      aT += a.x * wt[kk * 4 + 0] + a.y * wt[kk * 4 + 1] +
            a.z * wt[kk * 4 + 2] + a.w * wt[kk * 4 + 3];
      aI += bI.x * wi[kk * 4 + 0] + bI.y * wi[kk * 4 + 1] +
            bI.z * wi[kk * 4 + 2] + bI.w * wi[kk * 4 + 3];
      aR += r.x * wr[kk * 4 + 0] + r.y * wr[kk * 4 + 1] +
            r.z * wr[kk * 4 + 2] + r.w * wr[kk * 4 + 3];
    }
    float acc = dT * sb[j] + gate * sb[32 + j] + sb[64 + j] + aT + invI * aI + aR;
    hs2[li * 32 + j] = fmaxf(acc, 0.0f);
  }
  __syncthreads();
  if (t < 224) {
#pragma unroll
    for (int pass = 0; pass < CN * 7 / 224; ++pass) {
      int o = pass * 224 + t;
      int m = o / 7, jc = o - m * 7;
      int n = node0 + m;
      if (n < N) {
        float a = sbc[jc];
        const float* hp = hs2 + m * 32;
#pragma unroll
        for (int k = 0; k < 32; ++k) a += hp[k] * sWc[k * 7 + jc];
        out[(size_t)n * 7 + jc] = a;
      }
    }
  }
}

extern "C" void kernel_launch(void* const* d_in, const int* in_sizes, int n_in,
                              void* d_out, int out_size, void* d_ws,
                              size_t ws_size, hipStream_t stream) {
  const float* x   = (const float*)d_in[0];
  const int* ei_t  = (const int*)d_in[1];
  const int* ei_i  = (const int*)d_in[2];
  const float* W1t = (const float*)d_in[3];
  const float* b1t = (const float*)d_in[4];
  const float* W1i = (const float*)d_in[5];
  const float* b1i = (const float*)d_in[6];
  const float* W1r = (const float*)d_in[7];
  const float* b1r = (const float*)d_in[8];
  const float* W2t = (const float*)d_in[9];
  const float* b2t = (const float*)d_in[10];
  const float* W2i = (const float*)d_in[11];
  const float* b2i = (const float*)d_in[12];
  const float* W2r = (const float*)d_in[13];
  const float* b2r = (const float*)d_in[14];
  const float* Wc  = (const float*)d_in[15];
  const float* bc  = (const float*)d_in[16];
  float* out = (float*)d_out;

  const int N  = in_sizes[0] / 6;
  const int E  = in_sizes[1] / 2;
  const int Ei = in_sizes[2] / 2;
  const int K  = (N + RN - 1) / RN;
  const int halfN = N >> 1;   // halves must fit ushort: N <= 131070

  float* aggT = (float*)d_ws;
  float* aggI = aggT + (size_t)N * 32;
  unsigned short* h1b = (unsigned short*)(aggI + (size_t)N * 32);
  unsigned short* xp  = h1b + (size_t)N * 32;
  int* curT   = (int*)(xp + (size_t)N * 8);
  int* curI   = curT + KMAX;
  int* startT = curI + KMAX;
  int* degT   = startT + N;
  int* midT   = degT + N;
  int* startI = midT + N;
  int* degI   = startI + N;
  int* midI   = degI + N;
  int* binT   = midI + N;
  int* binI   = binT + (size_t)K * CAP;
  unsigned short* csrT = (unsigned short*)(binI + (size_t)K * CAP);
  unsigned short* csrI = csrT + (size_t)K * CAP;

  const int gN8  = (N * 8 + BLK - 1) / BLK;
  const int gG1  = (N + GN1 - 1) / GN1;
  const int gG2  = (N * 4 + BLK - 1) / BLK;
  const int gC2  = (N + CN - 1) / CN;
  const int Emax = (E > Ei) ? E : Ei;
  const int gBin = (Emax + CHUNK - 1) / CHUNK;

  // ---- build ----
  k_prep<<<gN8, BLK, 0, stream>>>(x, xp, curT, curI, N, K);
  k_bin3<<<dim3(gBin, 2), BLK, 0, stream>>>(ei_t, E, curT, binT, ei_i, Ei,
                                            curI, binI, K);
  k_sortcsr2m<<<dim3(K, 2), 512, 0, stream>>>(binT, curT, csrT, startT, degT,
                                              midT, binI, curI, csrI, startI,
                                              degI, midI, N, halfN);

  // ---- Layer 1 (fused gather+transform -> bf16 h1, LDS csr staging) ----
  k_g1c1<<<gG1, BLK, 0, stream>>>(xp, x, startT, degT, midT, csrT, startI,
                                  degI, midI, csrI, W1t, b1t, W1i, b1i, W1r,
                                  b1r, h1b, N, halfN);

  // ---- Layer 2 (src-half phased gather, then combine+cls) ----
  k_gather2<<<dim3(gG2, 2), BLK, 0, stream>>>(h1b, startT, degT, midT, csrT,
                                              startI, degI, midI, csrI, aggT,
                                              aggI, N, halfN);
  k_combine2cls<<<gC2, BLK, 0, stream>>>(aggT, aggI, h1b, degT, degI, W2t,
                                         b2t, W2i, b2i, W2r, b2r, Wc, bc, out,
                                         N);
}

// Round 12
// 237.888 us; speedup vs baseline: 1.3260x; 1.0022x over previous
//
#include <hip/hip_runtime.h>

// Round 31: r30 config verbatim (measured best 238.4us) with ONE change:
// k_sortcsr2m caches its bin[] entries in a statically-indexed 22-register
// array across the histogram->scatter passes (CAP/512 = 22 max per thread),
// eliminating the second global read of bin (~23MB + latency). Exact twin
// of r30's bin3 fix; the scattered/redundant-VMEM lever is 3-for-3.
// No layout, sync, or occupancy changes.
//
// ws: aggT[N*32] aggI[N*32] f32 | h1b[N*32] xp[N*8] bf16 | curT curI |
//     startT degT midT startI degI midI [N] | binT binI [K*CAP] int |
//     csrT csrI [K*CAP] ushort

#define BLK 256
#define RN 512            // nodes per bucket
#define KMAX 256          // max buckets (N <= 131072)
#define CAP 11264         // bucket capacity (mean 10204, +10 sigma)
#define CHUNK 4096        // edges per bin3 block
#define EPT 16            // edges per thread in bin3 (CHUNK/BLK)
#define BPT 22            // bin entries per thread in sortcsr (CAP/512)
#define CSRC 2048         // per-etype LDS csr cap in g1c1

typedef unsigned short us8 __attribute__((ext_vector_type(8)));

__device__ inline unsigned short f2bf(float f) {
  unsigned u = __float_as_uint(f);
  return (unsigned short)((u + 0x7FFFu + ((u >> 16) & 1u)) >> 16);
}
__device__ inline float bf2f(unsigned short h) {
  return __uint_as_float(((unsigned)h) << 16);
}

// ---------------- prep: x -> bf16 padded rows; init bucket cursors ----------
__global__ __launch_bounds__(BLK) void k_prep(const float* __restrict__ x,
                                              unsigned short* __restrict__ xp,
                                              int* __restrict__ curT,
                                              int* __restrict__ curI, int N,
                                              int K) {
  int gid = blockIdx.x * BLK + threadIdx.x;
  if (gid < K) {
    curT[gid] = gid * CAP;
    curI[gid] = gid * CAP;
  }
  if (gid >= N * 8) return;
  int n = gid >> 3, c = gid & 7;
  xp[gid] = (c < 6) ? f2bf(x[n * 6 + c]) : (unsigned short)0;
}

// ---------------- bin: LDS-staged local sort, register-cached edges --------
__global__ __launch_bounds__(BLK) void k_bin3(
    const int* __restrict__ eiT, int ET, int* __restrict__ curT,
    int* __restrict__ binT, const int* __restrict__ eiI, int EI,
    int* __restrict__ curI, int* __restrict__ binI, int K) {
  const int* ei = blockIdx.y ? eiI : eiT;
  int E = blockIdx.y ? EI : ET;
  int* gcur = blockIdx.y ? curI : curT;
  int* binned = blockIdx.y ? binI : binT;
  int cs = blockIdx.x * CHUNK;
  if (cs >= E) return;
  int ce = min(E, cs + CHUNK);
  int cnt = ce - cs;
  __shared__ int ebuf[CHUNK];
  __shared__ unsigned char bbuf[CHUNK];
  __shared__ int hist[KMAX], cur[KMAX], gdelta[KMAX], s[KMAX];
  int t = threadIdx.x;
  hist[t] = 0;
  __syncthreads();
  int rs[EPT], rd[EPT];
#pragma unroll
  for (int i = 0; i < EPT; ++i) {
    int e = cs + t + i * BLK;
    if (e < ce) {
      rs[i] = ei[e];
      rd[i] = ei[E + e];
      atomicAdd(&hist[rd[i] >> 9], 1);
    }
  }
  __syncthreads();
  int v = hist[t];
  s[t] = v;
  __syncthreads();
  for (int off = 1; off < KMAX; off <<= 1) {
    int x = (t >= off) ? s[t - off] : 0;
    __syncthreads();
    s[t] += x;
    __syncthreads();
  }
  int excl = s[t] - v;
  cur[t] = excl;
  if (t < K) gdelta[t] = atomicAdd(&gcur[t], v) - excl;
  __syncthreads();
#pragma unroll
  for (int i = 0; i < EPT; ++i) {
    int e = cs + t + i * BLK;
    if (e < ce) {
      int src = rs[i];
      int d = rd[i];
      int b = d >> 9;
      int slot = atomicAdd(&cur[b], 1);
      ebuf[slot] = (src << 9) | (d & 511);
      bbuf[slot] = (unsigned char)b;
    }
  }
  __syncthreads();
  for (int i = t; i < cnt; i += BLK) {
    int b = bbuf[i];
    __builtin_nontemporal_store(ebuf[i], &binned[i + gdelta[b]]);
  }
}

// per-bucket counting sort, (node, src-half) keys -> 16-bit csr + start/deg/mid
// bin entries register-cached across passes; scatter into LDS; coalesced out.
__global__ __launch_bounds__(512) void k_sortcsr2m(
    const int* __restrict__ binT, const int* __restrict__ curT,
    unsigned short* __restrict__ csrT, int* __restrict__ startT,
    int* __restrict__ degT, int* __restrict__ midT,
    const int* __restrict__ binI, const int* __restrict__ curI,
    unsigned short* __restrict__ csrI, int* __restrict__ startI,
    int* __restrict__ degI, int* __restrict__ midI, int N, int halfN) {
  const int* bin = blockIdx.y ? binI : binT;
  const int* cur = blockIdx.y ? curI : curT;
  unsigned short* csr = blockIdx.y ? csrI : csrT;
  int* start = blockIdx.y ? startI : startT;
  int* deg = blockIdx.y ? degI : degT;
  int* mid = blockIdx.y ? midI : midT;
  __shared__ int h[2 * RN], s[RN], c2[2 * RN];
  __shared__ unsigned short lcsr[CAP];
  int t = threadIdx.x, b = blockIdx.x;
  int e0 = b * CAP;
  int cnt = min(cur[b] - e0, CAP);
  h[t] = 0;
  h[t + RN] = 0;
  __syncthreads();
  int rp[BPT];
#pragma unroll
  for (int it = 0; it < BPT; ++it) {
    int i = t + it * 512;
    if (i < cnt) {
      int p = bin[e0 + i];
      rp[it] = p;
      int key = ((p & 511) << 1) | ((p >> 9) >= halfN ? 1 : 0);
      atomicAdd(&h[key], 1);
    }
  }
  __syncthreads();
  int lo = h[2 * t], hi = h[2 * t + 1];
  int pair = lo + hi;
  s[t] = pair;
  __syncthreads();
  for (int off = 1; off < 512; off <<= 1) {
    int v = (t >= off) ? s[t - off] : 0;
    __syncthreads();
    s[t] += v;
    __syncthreads();
  }
  int excl = s[t] - pair;
  c2[2 * t] = excl;
  c2[2 * t + 1] = excl + lo;
  int n = b * RN + t;
  if (n < N) {
    start[n] = e0 + excl;
    deg[n] = pair;
    mid[n] = e0 + excl + lo;
  }
  __syncthreads();
#pragma unroll
  for (int it = 0; it < BPT; ++it) {
    int i = t + it * 512;
    if (i < cnt) {
      int p = rp[it];
      int src = p >> 9;
      int hiFlag = (src >= halfN) ? 1 : 0;
      int key = ((p & 511) << 1) | hiFlag;
      int pos = atomicAdd(&c2[key], 1);
      lcsr[pos] = (unsigned short)(src - hiFlag * halfN);
    }
  }
  __syncthreads();
  // coalesced write-out (e0*2 bytes is 4B-aligned since CAP is even)
  unsigned int* dst = (unsigned int*)(csr + e0);
  const unsigned int* srcp = (const unsigned int*)lcsr;
  int cnt2 = cnt >> 1;
  for (int i = t; i < cnt2; i += 512) dst[i] = srcp[i];
  if (t == 0 && (cnt & 1)) csr[e0 + cnt - 1] = lcsr[cnt - 1];
}

// ------- fused layer 1: 8 thr/node (etype x src-half x edge-parity),
//         LDS-staged csr segments, full 16B row loads ----------
#define GN1 32
__global__ __launch_bounds__(BLK) void k_g1c1(
    const unsigned short* __restrict__ xp, const float* __restrict__ x,
    const int* __restrict__ startT, const int* __restrict__ degT,
    const int* __restrict__ midT, const unsigned short* __restrict__ csrT,
    const int* __restrict__ startI, const int* __restrict__ degI,
    const int* __restrict__ midI, const unsigned short* __restrict__ csrI,
    const float* __restrict__ Wt, const float* __restrict__ bt,
    const float* __restrict__ Wi, const float* __restrict__ bi,
    const float* __restrict__ Wr, const float* __restrict__ br,
    unsigned short* __restrict__ h1b, int N, int halfN) {
  __shared__ float sGT[GN1 * 32], sGI[GN1 * 32], sx[GN1 * 6];
  __shared__ float sWt[192], sWi[192], sWr[192], sb[96];
  __shared__ float sdT[GN1], sdI[GN1];
  __shared__ unsigned short lcT[CSRC], lcI[CSRC];
  __shared__ int sm[4];
  int t = threadIdx.x, b = blockIdx.x;
  if (t < 192) { sWt[t] = Wt[t]; sWi[t] = Wi[t]; sWr[t] = Wr[t]; }
  if (t < 32) { sb[t] = bt[t]; sb[32 + t] = bi[t]; sb[64 + t] = br[t]; }
  if (t < GN1 * 6) {
    int g = b * GN1 * 6 + t;
    sx[t] = (g < N * 6) ? x[g] : 0.0f;
  }
  int n0 = b * GN1;
  if (t == 0) {
    // block's 32 nodes are bucket-contiguous: csr segment per etype is one
    // contiguous run [start[n0], start[nL]+deg[nL])
    int nL = min(n0 + GN1, N) - 1;
    int bT = startT[n0];
    sm[0] = bT;
    sm[1] = startT[nL] + degT[nL] - bT;
    int bI = startI[n0];
    sm[2] = bI;
    sm[3] = startI[nL] + degI[nL] - bI;
  }
  __syncthreads();
  int baseT = sm[0], lenT = sm[1], baseI = sm[2], lenI = sm[3];
  {
    int lt = min(lenT, CSRC);
    for (int i = t; i < lt; i += BLK) lcT[i] = csrT[baseT + i];
    int li = min(lenI, CSRC);
    for (int i = t; i < li; i += BLK) lcI[i] = csrI[baseI + i];
  }
  __syncthreads();
  int nl = t >> 3, et = (t >> 2) & 1, half = (t >> 1) & 1, par = t & 1;
  int n = n0 + nl;
  float a[8] = {0.f, 0.f, 0.f, 0.f, 0.f, 0.f, 0.f, 0.f};
  int d = 0;
  if (n < N) {
    const int* startA = et ? startI : startT;
    const int* degA = et ? degI : degT;
    const int* midA = et ? midI : midT;
    int baseA = et ? baseI : baseT;
    int lenA = et ? lenI : lenT;
    const unsigned short* csrp =
        (lenA <= CSRC) ? (const unsigned short*)(et ? lcI : lcT)
                       : ((et ? csrI : csrT) + baseA);
    int s0 = startA[n];
    d = degA[n];
    int m = midA[n];
    int i0 = (half ? m : s0) - baseA;
    int i1 = (half ? (s0 + d) : m) - baseA;
    const unsigned short* tab = xp + (half ? (size_t)halfN * 8 : 0);
    int i = i0 + par;
    for (; i + 6 < i1; i += 8) {
      int r0 = csrp[i], r1 = csrp[i + 2], r2 = csrp[i + 4], r3 = csrp[i + 6];
      us8 v0 = *(const us8*)(tab + (size_t)r0 * 8);
      us8 v1 = *(const us8*)(tab + (size_t)r1 * 8);
      us8 v2 = *(const us8*)(tab + (size_t)r2 * 8);
      us8 v3 = *(const us8*)(tab + (size_t)r3 * 8);
#pragma unroll
      for (int k = 0; k < 8; ++k)
        a[k] += (bf2f(v0[k]) + bf2f(v1[k])) + (bf2f(v2[k]) + bf2f(v3[k]));
    }
    for (; i < i1; i += 2) {
      int r0 = csrp[i];
      us8 v0 = *(const us8*)(tab + (size_t)r0 * 8);
#pragma unroll
      for (int k = 0; k < 8; ++k) a[k] += bf2f(v0[k]);
    }
  }
  // slot = half*2 + par; 4 slots x 8ch = 32 floats per (node, etype)
  float* dst = (et ? sGI : sGT) + nl * 32 + (half * 2 + par) * 8;
#pragma unroll
  for (int k = 0; k < 8; ++k) dst[k] = a[k];
  if (half == 0 && par == 0) {
    if (et) sdI[nl] = (float)d;
    else    sdT[nl] = (float)d;
  }
  __syncthreads();
  for (int idx = t; idx < GN1 * 32; idx += BLK) {
    int m = idx >> 5, j = idx & 31;
    int nn = n0 + m;
    if (nn >= N) break;
    float fdT = sdT[m], fdI = sdI[m];
    float invI = 1.0f / fmaxf(fdI, 1.0f);
    float gate = (fdI > 0.0f) ? 1.0f : 0.0f;
    float acc = fdT * sb[j] + gate * sb[32 + j] + sb[64 + j];
#pragma unroll
    for (int k = 0; k < 6; ++k) {
      float gT = sGT[m * 32 + k] + sGT[m * 32 + 8 + k] +
                 sGT[m * 32 + 16 + k] + sGT[m * 32 + 24 + k];
      float gI = sGI[m * 32 + k] + sGI[m * 32 + 8 + k] +
                 sGI[m * 32 + 16 + k] + sGI[m * 32 + 24 + k];
      acc += gT * sWt[k * 32 + j];
      acc += gI * invI * sWi[k * 32 + j];
      acc += sx[m * 6 + k] * sWr[k * 32 + j];
    }
    h1b[(size_t)nn * 32 + j] = f2bf(fmaxf(acc, 0.0f));
  }
}

// ---------------- layer-2 gather helper: unroll-4, 16B bf16 loads ----------
__device__ inline void accum8(const unsigned short* __restrict__ tab,
                              const unsigned short* __restrict__ csr, int i0,
                              int i1, float* a) {
  int i = i0;
  for (; i + 4 <= i1; i += 4) {
    int r0 = csr[i], r1 = csr[i + 1], r2 = csr[i + 2], r3 = csr[i + 3];
    us8 v0 = *(const us8*)(tab + (size_t)r0 * 32);
    us8 v1 = *(const us8*)(tab + (size_t)r1 * 32);
    us8 v2 = *(const us8*)(tab + (size_t)r2 * 32);
    us8 v3 = *(const us8*)(tab + (size_t)r3 * 32);
#pragma unroll
    for (int k = 0; k < 8; ++k)
      a[k] += (bf2f(v0[k]) + bf2f(v1[k])) + (bf2f(v2[k]) + bf2f(v3[k]));
  }
  for (; i < i1; ++i) {
    int r0 = csr[i];
    us8 v0 = *(const us8*)(tab + (size_t)r0 * 32);
#pragma unroll
    for (int k = 0; k < 8; ++k) a[k] += bf2f(v0[k]);
  }
}

// --- layer-2 gather: 4 thr/node (chan-quarter), src-half phased (r19) ------
__global__ __launch_bounds__(BLK) void k_gather2(
    const unsigned short* __restrict__ h1b, const int* __restrict__ startT,
    const int* __restrict__ degT, const int* __restrict__ midT,
    const unsigned short* __restrict__ csrT, const int* __restrict__ startI,
    const int* __restrict__ degI, const int* __restrict__ midI,
    const unsigned short* __restrict__ csrI, float* __restrict__ aggT,
    float* __restrict__ aggI, int N, int halfN) {
  const int* start = blockIdx.y ? startI : startT;
  const int* deg = blockIdx.y ? degI : degT;
  const int* mid = blockIdx.y ? midI : midT;
  const unsigned short* csr = blockIdx.y ? csrI : csrT;
  float* agg = blockIdx.y ? aggI : aggT;
  int gid = blockIdx.x * BLK + threadIdx.x;
  int n = gid >> 2;
  if (n >= N) return;
  int c8 = (gid & 3) * 8;
  float a[8] = {0.f, 0.f, 0.f, 0.f, 0.f, 0.f, 0.f, 0.f};
  int s0 = start[n], d = deg[n], m = mid[n];
  // phase 0: src < N/2 (lower table half L2-resident chip-wide), then phase 1
  accum8(h1b + c8, csr, s0, m, a);
  accum8(h1b + (size_t)halfN * 32 + c8, csr, m, s0 + d, a);
  float* p = agg + (size_t)n * 32 + c8;
#pragma unroll
  for (int k = 0; k < 8; ++k) __builtin_nontemporal_store(a[k], p + k);
}

// ------- combine2 + classifier: one-barrier full staging, reg weights ------
#define CN 64
__global__ __launch_bounds__(BLK) void k_combine2cls(
    const float* __restrict__ aggT, const float* __restrict__ aggI,
    const unsigned short* __restrict__ h1b, const int* __restrict__ degT,
    const int* __restrict__ degI, const float* __restrict__ Wt,
    const float* __restrict__ bt, const float* __restrict__ Wi,
    const float* __restrict__ bi, const float* __restrict__ Wr,
    const float* __restrict__ br, const float* __restrict__ Wc,
    const float* __restrict__ bc, float* __restrict__ out, int N) {
  __shared__ float hTs[CN * 32], hIs[CN * 32], hRs[CN * 32], hs2[CN * 32];
  __shared__ float sWc[224], sbc[7], sb[96];
  __shared__ float sdT[CN], sdI[CN];
  int t = threadIdx.x;
  int j = t & 31, ln = t >> 5;
  float wt[32], wi[32], wr[32];
#pragma unroll
  for (int k = 0; k < 32; ++k) {
    wt[k] = Wt[k * 32 + j];
    wi[k] = Wi[k * 32 + j];
    wr[k] = Wr[k * 32 + j];
  }
  int node0 = blockIdx.x * CN;
  size_t gbase = (size_t)node0 * 32;
  {
    const float4* sT = (const float4*)(aggT + gbase);
    const float4* sI = (const float4*)(aggI + gbase);
    ((float4*)hTs)[t] = sT[t];
    ((float4*)hTs)[t + 256] = sT[t + 256];
    ((float4*)hIs)[t] = sI[t];
    ((float4*)hIs)[t + 256] = sI[t + 256];
    us8 v = ((const us8*)(h1b + gbase))[t];
    float4 lo = {bf2f(v[0]), bf2f(v[1]), bf2f(v[2]), bf2f(v[3])};
    float4 hi = {bf2f(v[4]), bf2f(v[5]), bf2f(v[6]), bf2f(v[7])};
    ((float4*)hRs)[2 * t] = lo;
    ((float4*)hRs)[2 * t + 1] = hi;
  }
  if (t < 224) sWc[t] = Wc[t];
  if (t < 7) sbc[t] = bc[t];
  if (t < 32) { sb[t] = bt[t]; sb[32 + t] = bi[t]; sb[64 + t] = br[t]; }
  if (t < CN) {
    int n = node0 + t;
    sdT[t] = (n < N) ? (float)degT[n] : 0.f;
    sdI[t] = (n < N) ? (float)degI[n] : 0.f;
  }
  __syncthreads();
#pragma unroll
  for (int it = 0; it < CN / 8; ++it) {
    int li = it * 8 + ln;
    float dT = sdT[li], dI = sdI[li];
    float invI = 1.0f / fmaxf(dI, 1.0f);
    float gate = (dI > 0.0f) ? 1.0f : 0.0f;
    float aT = 0.f, aI = 0.f, aR = 0.f;
    const float4* hT4 = (const float4*)(hTs + li * 32);
    const float4* hI4 = (const float4*)(hIs + li * 32);
    const float4* hR4 = (const float4*)(hRs + li * 32);
#pragma unroll
    for (int kk = 0; kk < 8; ++kk) {
      float4 a = hT4[kk], bI = hI4[kk], r = hR4[kk];
      aT += a.x * wt[kk * 4 + 0] + a.y * wt[kk * 4 + 1] +
            a.z * wt[kk * 4 + 2] + a.w * wt[kk * 4 + 3];
      aI += bI.x * wi[kk * 4 + 0] + bI.y * wi[kk * 4 + 1] +
            bI.z * wi[kk * 4 + 2] + bI.w * wi[kk * 4 + 3];
      aR += r.x * wr[kk * 4 + 0] + r.y * wr[kk * 4 + 1] +
            r.z * wr[kk * 4 + 2] + r.w * wr[kk * 4 + 3];
    }
    float acc = dT * sb[j] + gate * sb[32 + j] + sb[64 + j] + aT + invI * aI + aR;
    hs2[li * 32 + j] = fmaxf(acc, 0.0f);
  }
  __syncthreads();
  if (t < 224) {
#pragma unroll
    for (int pass = 0; pass < CN * 7 / 224; ++pass) {
      int o = pass * 224 + t;
      int m = o / 7, jc = o - m * 7;
      int n = node0 + m;
      if (n < N) {
        float a = sbc[jc];
        const float* hp = hs2 + m * 32;
#pragma unroll
        for (int k = 0; k < 32; ++k) a += hp[k] * sWc[k * 7 + jc];
        out[(size_t)n * 7 + jc] = a;
      }
    }
  }
}

extern "C" void kernel_launch(void* const* d_in, const int* in_sizes, int n_in,
                              void* d_out, int out_size, void* d_ws,
                              size_t ws_size, hipStream_t stream) {
  const float* x   = (const float*)d_in[0];
  const int* ei_t  = (const int*)d_in[1];
  const int* ei_i  = (const int*)d_in[2];
  const float* W1t = (const float*)d_in[3];
  const float* b1t = (const float*)d_in[4];
  const float* W1i = (const float*)d_in[5];
  const float* b1i = (const float*)d_in[6];
  const float* W1r = (const float*)d_in[7];
  const float* b1r = (const float*)d_in[8];
  const float* W2t = (const float*)d_in[9];
  const float* b2t = (const float*)d_in[10];
  const float* W2i = (const float*)d_in[11];
  const float* b2i = (const float*)d_in[12];
  const float* W2r = (const float*)d_in[13];
  const float* b2r = (const float*)d_in[14];
  const float* Wc  = (const float*)d_in[15];
  const float* bc  = (const float*)d_in[16];
  float* out = (float*)d_out;

  const int N  = in_sizes[0] / 6;
  const int E  = in_sizes[1] / 2;
  const int Ei = in_sizes[2] / 2;
  const int K  = (N + RN - 1) / RN;
  const int halfN = N >> 1;   // halves must fit ushort: N <= 131070

  float* aggT = (float*)d_ws;
  float* aggI = aggT + (size_t)N * 32;
  unsigned short* h1b = (unsigned short*)(aggI + (size_t)N * 32);
  unsigned short* xp  = h1b + (size_t)N * 32;
  int* curT   = (int*)(xp + (size_t)N * 8);
  int* curI   = curT + KMAX;
  int* startT = curI + KMAX;
  int* degT   = startT + N;
  int* midT   = degT + N;
  int* startI = midT + N;
  int* degI   = startI + N;
  int* midI   = degI + N;
  int* binT   = midI + N;
  int* binI   = binT + (size_t)K * CAP;
  unsigned short* csrT = (unsigned short*)(binI + (size_t)K * CAP);
  unsigned short* csrI = csrT + (size_t)K * CAP;

  const int gN8  = (N * 8 + BLK - 1) / BLK;
  const int gG1  = (N + GN1 - 1) / GN1;
  const int gG2  = (N * 4 + BLK - 1) / BLK;
  const int gC2  = (N + CN - 1) / CN;
  const int Emax = (E > Ei) ? E : Ei;
  const int gBin = (Emax + CHUNK - 1) / CHUNK;

  // ---- build ----
  k_prep<<<gN8, BLK, 0, stream>>>(x, xp, curT, curI, N, K);
  k_bin3<<<dim3(gBin, 2), BLK, 0, stream>>>(ei_t, E, curT, binT, ei_i, Ei,
                                            curI, binI, K);
  k_sortcsr2m<<<dim3(K, 2), 512, 0, stream>>>(binT, curT, csrT, startT, degT,
                                              midT, binI, curI, csrI, startI,
                                              degI, midI, N, halfN);

  // ---- Layer 1 (fused gather+transform -> bf16 h1, LDS csr staging) ----
  k_g1c1<<<gG1, BLK, 0, stream>>>(xp, x, startT, degT, midT, csrT, startI,
                                  degI, midI, csrI, W1t, b1t, W1i, b1i, W1r,
                                  b1r, h1b, N, halfN);

  // ---- Layer 2 (src-half phased gather, then combine+cls) ----
  k_gather2<<<dim3(gG2, 2), BLK, 0, stream>>>(h1b, startT, degT, midT, csrT,
                                              startI, degI, midI, csrI, aggT,
                                              aggI, N, halfN);
  k_combine2cls<<<gC2, BLK, 0, stream>>>(aggT, aggI, h1b, degT, degI, W2t,
                                         b2t, W2i, b2i, W2r, b2r, Wc, bc, out,
                                         N);
}

// Round 13
// 235.767 us; speedup vs baseline: 1.3379x; 1.0090x over previous
//
#include <hip/hip_runtime.h>

// Round 32: r31 config verbatim (measured best 237.9us) with ONE change:
// k_combine2cls v4 = r17 structure (proven LDS staging, j-lane matvec) but
// the three 32x32 matvecs run as SEQUENTIAL PHASES sharing one w[32]
// register array (reload weights between phases; hs2 cell is thread-private
// so no inter-phase barrier). Peak VGPR ~150 -> ~75: no spill cliff,
// occupancy 12 -> 16 waves/CU. r27/r28 reconciliation: v2 spilled in the
// FMA loop (wall +64us), v3's rocprof-90us never showed on the wall ->
// r17-combine's true wall cost ~30us vs ~8us floor, and its defect is the
// 96 simultaneous weight VGPRs.
//
// ws: aggT[N*32] aggI[N*32] f32 | h1b[N*32] xp[N*8] bf16 | curT curI |
//     startT degT midT startI degI midI [N] | binT binI [K*CAP] int |
//     csrT csrI [K*CAP] ushort

#define BLK 256
#define RN 512            // nodes per bucket
#define KMAX 256          // max buckets (N <= 131072)
#define CAP 11264         // bucket capacity (mean 10204, +10 sigma)
#define CHUNK 4096        // edges per bin3 block
#define EPT 16            // edges per thread in bin3 (CHUNK/BLK)
#define BPT 22            // bin entries per thread in sortcsr (CAP/512)
#define CSRC 2048         // per-etype LDS csr cap in g1c1

typedef unsigned short us8 __attribute__((ext_vector_type(8)));

__device__ inline unsigned short f2bf(float f) {
  unsigned u = __float_as_uint(f);
  return (unsigned short)((u + 0x7FFFu + ((u >> 16) & 1u)) >> 16);
}
__device__ inline float bf2f(unsigned short h) {
  return __uint_as_float(((unsigned)h) << 16);
}

// ---------------- prep: x -> bf16 padded rows; init bucket cursors ----------
__global__ __launch_bounds__(BLK) void k_prep(const float* __restrict__ x,
                                              unsigned short* __restrict__ xp,
                                              int* __restrict__ curT,
                                              int* __restrict__ curI, int N,
                                              int K) {
  int gid = blockIdx.x * BLK + threadIdx.x;
  if (gid < K) {
    curT[gid] = gid * CAP;
    curI[gid] = gid * CAP;
  }
  if (gid >= N * 8) return;
  int n = gid >> 3, c = gid & 7;
  xp[gid] = (c < 6) ? f2bf(x[n * 6 + c]) : (unsigned short)0;
}

// ---------------- bin: LDS-staged local sort, register-cached edges --------
__global__ __launch_bounds__(BLK) void k_bin3(
    const int* __restrict__ eiT, int ET, int* __restrict__ curT,
    int* __restrict__ binT, const int* __restrict__ eiI, int EI,
    int* __restrict__ curI, int* __restrict__ binI, int K) {
  const int* ei = blockIdx.y ? eiI : eiT;
  int E = blockIdx.y ? EI : ET;
  int* gcur = blockIdx.y ? curI : curT;
  int* binned = blockIdx.y ? binI : binT;
  int cs = blockIdx.x * CHUNK;
  if (cs >= E) return;
  int ce = min(E, cs + CHUNK);
  int cnt = ce - cs;
  __shared__ int ebuf[CHUNK];
  __shared__ unsigned char bbuf[CHUNK];
  __shared__ int hist[KMAX], cur[KMAX], gdelta[KMAX], s[KMAX];
  int t = threadIdx.x;
  hist[t] = 0;
  __syncthreads();
  int rs[EPT], rd[EPT];
#pragma unroll
  for (int i = 0; i < EPT; ++i) {
    int e = cs + t + i * BLK;
    if (e < ce) {
      rs[i] = ei[e];
      rd[i] = ei[E + e];
      atomicAdd(&hist[rd[i] >> 9], 1);
    }
  }
  __syncthreads();
  int v = hist[t];
  s[t] = v;
  __syncthreads();
  for (int off = 1; off < KMAX; off <<= 1) {
    int x = (t >= off) ? s[t - off] : 0;
    __syncthreads();
    s[t] += x;
    __syncthreads();
  }
  int excl = s[t] - v;
  cur[t] = excl;
  if (t < K) gdelta[t] = atomicAdd(&gcur[t], v) - excl;
  __syncthreads();
#pragma unroll
  for (int i = 0; i < EPT; ++i) {
    int e = cs + t + i * BLK;
    if (e < ce) {
      int src = rs[i];
      int d = rd[i];
      int b = d >> 9;
      int slot = atomicAdd(&cur[b], 1);
      ebuf[slot] = (src << 9) | (d & 511);
      bbuf[slot] = (unsigned char)b;
    }
  }
  __syncthreads();
  for (int i = t; i < cnt; i += BLK) {
    int b = bbuf[i];
    __builtin_nontemporal_store(ebuf[i], &binned[i + gdelta[b]]);
  }
}

// per-bucket counting sort, (node, src-half) keys -> 16-bit csr + start/deg/mid
// bin entries register-cached across passes; scatter into LDS; coalesced out.
__global__ __launch_bounds__(512) void k_sortcsr2m(
    const int* __restrict__ binT, const int* __restrict__ curT,
    unsigned short* __restrict__ csrT, int* __restrict__ startT,
    int* __restrict__ degT, int* __restrict__ midT,
    const int* __restrict__ binI, const int* __restrict__ curI,
    unsigned short* __restrict__ csrI, int* __restrict__ startI,
    int* __restrict__ degI, int* __restrict__ midI, int N, int halfN) {
  const int* bin = blockIdx.y ? binI : binT;
  const int* cur = blockIdx.y ? curI : curT;
  unsigned short* csr = blockIdx.y ? csrI : csrT;
  int* start = blockIdx.y ? startI : startT;
  int* deg = blockIdx.y ? degI : degT;
  int* mid = blockIdx.y ? midI : midT;
  __shared__ int h[2 * RN], s[RN], c2[2 * RN];
  __shared__ unsigned short lcsr[CAP];
  int t = threadIdx.x, b = blockIdx.x;
  int e0 = b * CAP;
  int cnt = min(cur[b] - e0, CAP);
  h[t] = 0;
  h[t + RN] = 0;
  __syncthreads();
  int rp[BPT];
#pragma unroll
  for (int it = 0; it < BPT; ++it) {
    int i = t + it * 512;
    if (i < cnt) {
      int p = bin[e0 + i];
      rp[it] = p;
      int key = ((p & 511) << 1) | ((p >> 9) >= halfN ? 1 : 0);
      atomicAdd(&h[key], 1);
    }
  }
  __syncthreads();
  int lo = h[2 * t], hi = h[2 * t + 1];
  int pair = lo + hi;
  s[t] = pair;
  __syncthreads();
  for (int off = 1; off < 512; off <<= 1) {
    int v = (t >= off) ? s[t - off] : 0;
    __syncthreads();
    s[t] += v;
    __syncthreads();
  }
  int excl = s[t] - pair;
  c2[2 * t] = excl;
  c2[2 * t + 1] = excl + lo;
  int n = b * RN + t;
  if (n < N) {
    start[n] = e0 + excl;
    deg[n] = pair;
    mid[n] = e0 + excl + lo;
  }
  __syncthreads();
#pragma unroll
  for (int it = 0; it < BPT; ++it) {
    int i = t + it * 512;
    if (i < cnt) {
      int p = rp[it];
      int src = p >> 9;
      int hiFlag = (src >= halfN) ? 1 : 0;
      int key = ((p & 511) << 1) | hiFlag;
      int pos = atomicAdd(&c2[key], 1);
      lcsr[pos] = (unsigned short)(src - hiFlag * halfN);
    }
  }
  __syncthreads();
  // coalesced write-out (e0*2 bytes is 4B-aligned since CAP is even)
  unsigned int* dst = (unsigned int*)(csr + e0);
  const unsigned int* srcp = (const unsigned int*)lcsr;
  int cnt2 = cnt >> 1;
  for (int i = t; i < cnt2; i += 512) dst[i] = srcp[i];
  if (t == 0 && (cnt & 1)) csr[e0 + cnt - 1] = lcsr[cnt - 1];
}

// ------- fused layer 1: 8 thr/node (etype x src-half x edge-parity),
//         LDS-staged csr segments, full 16B row loads ----------
#define GN1 32
__global__ __launch_bounds__(BLK) void k_g1c1(
    const unsigned short* __restrict__ xp, const float* __restrict__ x,
    const int* __restrict__ startT, const int* __restrict__ degT,
    const int* __restrict__ midT, const unsigned short* __restrict__ csrT,
    const int* __restrict__ startI, const int* __restrict__ degI,
    const int* __restrict__ midI, const unsigned short* __restrict__ csrI,
    const float* __restrict__ Wt, const float* __restrict__ bt,
    const float* __restrict__ Wi, const float* __restrict__ bi,
    const float* __restrict__ Wr, const float* __restrict__ br,
    unsigned short* __restrict__ h1b, int N, int halfN) {
  __shared__ float sGT[GN1 * 32], sGI[GN1 * 32], sx[GN1 * 6];
  __shared__ float sWt[192], sWi[192], sWr[192], sb[96];
  __shared__ float sdT[GN1], sdI[GN1];
  __shared__ unsigned short lcT[CSRC], lcI[CSRC];
  __shared__ int sm[4];
  int t = threadIdx.x, b = blockIdx.x;
  if (t < 192) { sWt[t] = Wt[t]; sWi[t] = Wi[t]; sWr[t] = Wr[t]; }
  if (t < 32) { sb[t] = bt[t]; sb[32 + t] = bi[t]; sb[64 + t] = br[t]; }
  if (t < GN1 * 6) {
    int g = b * GN1 * 6 + t;
    sx[t] = (g < N * 6) ? x[g] : 0.0f;
  }
  int n0 = b * GN1;
  if (t == 0) {
    // block's 32 nodes are bucket-contiguous: csr segment per etype is one
    // contiguous run [start[n0], start[nL]+deg[nL])
    int nL = min(n0 + GN1, N) - 1;
    int bT = startT[n0];
    sm[0] = bT;
    sm[1] = startT[nL] + degT[nL] - bT;
    int bI = startI[n0];
    sm[2] = bI;
    sm[3] = startI[nL] + degI[nL] - bI;
  }
  __syncthreads();
  int baseT = sm[0], lenT = sm[1], baseI = sm[2], lenI = sm[3];
  {
    int lt = min(lenT, CSRC);
    for (int i = t; i < lt; i += BLK) lcT[i] = csrT[baseT + i];
    int li = min(lenI, CSRC);
    for (int i = t; i < li; i += BLK) lcI[i] = csrI[baseI + i];
  }
  __syncthreads();
  int nl = t >> 3, et = (t >> 2) & 1, half = (t >> 1) & 1, par = t & 1;
  int n = n0 + nl;
  float a[8] = {0.f, 0.f, 0.f, 0.f, 0.f, 0.f, 0.f, 0.f};
  int d = 0;
  if (n < N) {
    const int* startA = et ? startI : startT;
    const int* degA = et ? degI : degT;
    const int* midA = et ? midI : midT;
    int baseA = et ? baseI : baseT;
    int lenA = et ? lenI : lenT;
    const unsigned short* csrp =
        (lenA <= CSRC) ? (const unsigned short*)(et ? lcI : lcT)
                       : ((et ? csrI : csrT) + baseA);
    int s0 = startA[n];
    d = degA[n];
    int m = midA[n];
    int i0 = (half ? m : s0) - baseA;
    int i1 = (half ? (s0 + d) : m) - baseA;
    const unsigned short* tab = xp + (half ? (size_t)halfN * 8 : 0);
    int i = i0 + par;
    for (; i + 6 < i1; i += 8) {
      int r0 = csrp[i], r1 = csrp[i + 2], r2 = csrp[i + 4], r3 = csrp[i + 6];
      us8 v0 = *(const us8*)(tab + (size_t)r0 * 8);
      us8 v1 = *(const us8*)(tab + (size_t)r1 * 8);
      us8 v2 = *(const us8*)(tab + (size_t)r2 * 8);
      us8 v3 = *(const us8*)(tab + (size_t)r3 * 8);
#pragma unroll
      for (int k = 0; k < 8; ++k)
        a[k] += (bf2f(v0[k]) + bf2f(v1[k])) + (bf2f(v2[k]) + bf2f(v3[k]));
    }
    for (; i < i1; i += 2) {
      int r0 = csrp[i];
      us8 v0 = *(const us8*)(tab + (size_t)r0 * 8);
#pragma unroll
      for (int k = 0; k < 8; ++k) a[k] += bf2f(v0[k]);
    }
  }
  // slot = half*2 + par; 4 slots x 8ch = 32 floats per (node, etype)
  float* dst = (et ? sGI : sGT) + nl * 32 + (half * 2 + par) * 8;
#pragma unroll
  for (int k = 0; k < 8; ++k) dst[k] = a[k];
  if (half == 0 && par == 0) {
    if (et) sdI[nl] = (float)d;
    else    sdT[nl] = (float)d;
  }
  __syncthreads();
  for (int idx = t; idx < GN1 * 32; idx += BLK) {
    int m = idx >> 5, j = idx & 31;
    int nn = n0 + m;
    if (nn >= N) break;
    float fdT = sdT[m], fdI = sdI[m];
    float invI = 1.0f / fmaxf(fdI, 1.0f);
    float gate = (fdI > 0.0f) ? 1.0f : 0.0f;
    float acc = fdT * sb[j] + gate * sb[32 + j] + sb[64 + j];
#pragma unroll
    for (int k = 0; k < 6; ++k) {
      float gT = sGT[m * 32 + k] + sGT[m * 32 + 8 + k] +
                 sGT[m * 32 + 16 + k] + sGT[m * 32 + 24 + k];
      float gI = sGI[m * 32 + k] + sGI[m * 32 + 8 + k] +
                 sGI[m * 32 + 16 + k] + sGI[m * 32 + 24 + k];
      acc += gT * sWt[k * 32 + j];
      acc += gI * invI * sWi[k * 32 + j];
      acc += sx[m * 6 + k] * sWr[k * 32 + j];
    }
    h1b[(size_t)nn * 32 + j] = f2bf(fmaxf(acc, 0.0f));
  }
}

// ---------------- layer-2 gather helper: unroll-4, 16B bf16 loads ----------
__device__ inline void accum8(const unsigned short* __restrict__ tab,
                              const unsigned short* __restrict__ csr, int i0,
                              int i1, float* a) {
  int i = i0;
  for (; i + 4 <= i1; i += 4) {
    int r0 = csr[i], r1 = csr[i + 1], r2 = csr[i + 2], r3 = csr[i + 3];
    us8 v0 = *(const us8*)(tab + (size_t)r0 * 32);
    us8 v1 = *(const us8*)(tab + (size_t)r1 * 32);
    us8 v2 = *(const us8*)(tab + (size_t)r2 * 32);
    us8 v3 = *(const us8*)(tab + (size_t)r3 * 32);
#pragma unroll
    for (int k = 0; k < 8; ++k)
      a[k] += (bf2f(v0[k]) + bf2f(v1[k])) + (bf2f(v2[k]) + bf2f(v3[k]));
  }
  for (; i < i1; ++i) {
    int r0 = csr[i];
    us8 v0 = *(const us8*)(tab + (size_t)r0 * 32);
#pragma unroll
    for (int k = 0; k < 8; ++k) a[k] += bf2f(v0[k]);
  }
}

// --- layer-2 gather: 4 thr/node (chan-quarter), src-half phased (r19) ------
__global__ __launch_bounds__(BLK) void k_gather2(
    const unsigned short* __restrict__ h1b, const int* __restrict__ startT,
    const int* __restrict__ degT, const int* __restrict__ midT,
    const unsigned short* __restrict__ csrT, const int* __restrict__ startI,
    const int* __restrict__ degI, const int* __restrict__ midI,
    const unsigned short* __restrict__ csrI, float* __restrict__ aggT,
    float* __restrict__ aggI, int N, int halfN) {
  const int* start = blockIdx.y ? startI : startT;
  const int* deg = blockIdx.y ? degI : degT;
  const int* mid = blockIdx.y ? midI : midT;
  const unsigned short* csr = blockIdx.y ? csrI : csrT;
  float* agg = blockIdx.y ? aggI : aggT;
  int gid = blockIdx.x * BLK + threadIdx.x;
  int n = gid >> 2;
  if (n >= N) return;
  int c8 = (gid & 3) * 8;
  float a[8] = {0.f, 0.f, 0.f, 0.f, 0.f, 0.f, 0.f, 0.f};
  int s0 = start[n], d = deg[n], m = mid[n];
  // phase 0: src < N/2 (lower table half L2-resident chip-wide), then phase 1
  accum8(h1b + c8, csr, s0, m, a);
  accum8(h1b + (size_t)halfN * 32 + c8, csr, m, s0 + d, a);
  float* p = agg + (size_t)n * 32 + c8;
#pragma unroll
  for (int k = 0; k < 8; ++k) __builtin_nontemporal_store(a[k], p + k);
}

// ------- combine2 + classifier v4: r17 staging, PHASE-WISE reg weights -----
#define CN 64
__global__ __launch_bounds__(BLK) void k_combine2cls(
    const float* __restrict__ aggT, const float* __restrict__ aggI,
    const unsigned short* __restrict__ h1b, const int* __restrict__ degT,
    const int* __restrict__ degI, const float* __restrict__ Wt,
    const float* __restrict__ bt, const float* __restrict__ Wi,
    const float* __restrict__ bi, const float* __restrict__ Wr,
    const float* __restrict__ br, const float* __restrict__ Wc,
    const float* __restrict__ bc, float* __restrict__ out, int N) {
  __shared__ float hTs[CN * 32], hIs[CN * 32], hRs[CN * 32], hs2[CN * 32];
  __shared__ float sWc[224], sbc[7], sb[96];
  __shared__ float sdT[CN], sdI[CN];
  int t = threadIdx.x;
  int j = t & 31, ln = t >> 5;
  int node0 = blockIdx.x * CN;
  size_t gbase = (size_t)node0 * 32;
  {
    const float4* sT = (const float4*)(aggT + gbase);
    const float4* sI = (const float4*)(aggI + gbase);
    ((float4*)hTs)[t] = sT[t];
    ((float4*)hTs)[t + 256] = sT[t + 256];
    ((float4*)hIs)[t] = sI[t];
    ((float4*)hIs)[t + 256] = sI[t + 256];
    us8 v = ((const us8*)(h1b + gbase))[t];
    float4 lo = {bf2f(v[0]), bf2f(v[1]), bf2f(v[2]), bf2f(v[3])};
    float4 hi = {bf2f(v[4]), bf2f(v[5]), bf2f(v[6]), bf2f(v[7])};
    ((float4*)hRs)[2 * t] = lo;
    ((float4*)hRs)[2 * t + 1] = hi;
  }
  if (t < 224) sWc[t] = Wc[t];
  if (t < 7) sbc[t] = bc[t];
  if (t < 32) { sb[t] = bt[t]; sb[32 + t] = bi[t]; sb[64 + t] = br[t]; }
  if (t < CN) {
    int n = node0 + t;
    sdT[t] = (n < N) ? (float)degT[n] : 0.f;
    sdI[t] = (n < N) ? (float)degI[n] : 0.f;
  }
  float w[32];
  __syncthreads();
  // ---- phase T: base + aggT @ Wt ----
#pragma unroll
  for (int k = 0; k < 32; ++k) w[k] = Wt[k * 32 + j];
#pragma unroll
  for (int it = 0; it < CN / 8; ++it) {
    int li = it * 8 + ln;
    float dT = sdT[li], dI = sdI[li];
    float gate = (dI > 0.0f) ? 1.0f : 0.0f;
    float aT = 0.f;
    const float4* h4 = (const float4*)(hTs + li * 32);
#pragma unroll
    for (int kk = 0; kk < 8; ++kk) {
      float4 a = h4[kk];
      aT += a.x * w[kk * 4 + 0] + a.y * w[kk * 4 + 1] +
            a.z * w[kk * 4 + 2] + a.w * w[kk * 4 + 3];
    }
    hs2[li * 32 + j] = dT * sb[j] + gate * sb[32 + j] + sb[64 + j] + aT;
  }
  // ---- phase I: += invI * (aggI @ Wi) ----
#pragma unroll
  for (int k = 0; k < 32; ++k) w[k] = Wi[k * 32 + j];
#pragma unroll
  for (int it = 0; it < CN / 8; ++it) {
    int li = it * 8 + ln;
    float invI = 1.0f / fmaxf(sdI[li], 1.0f);
    float aI = 0.f;
    const float4* h4 = (const float4*)(hIs + li * 32);
#pragma unroll
    for (int kk = 0; kk < 8; ++kk) {
      float4 a = h4[kk];
      aI += a.x * w[kk * 4 + 0] + a.y * w[kk * 4 + 1] +
            a.z * w[kk * 4 + 2] + a.w * w[kk * 4 + 3];
    }
    hs2[li * 32 + j] += invI * aI;
  }
  // ---- phase R: += h1 @ Wr, then ReLU ----
#pragma unroll
  for (int k = 0; k < 32; ++k) w[k] = Wr[k * 32 + j];
#pragma unroll
  for (int it = 0; it < CN / 8; ++it) {
    int li = it * 8 + ln;
    float aR = 0.f;
    const float4* h4 = (const float4*)(hRs + li * 32);
#pragma unroll
    for (int kk = 0; kk < 8; ++kk) {
      float4 a = h4[kk];
      aR += a.x * w[kk * 4 + 0] + a.y * w[kk * 4 + 1] +
            a.z * w[kk * 4 + 2] + a.w * w[kk * 4 + 3];
    }
    hs2[li * 32 + j] = fmaxf(hs2[li * 32 + j] + aR, 0.0f);
  }
  __syncthreads();
  if (t < 224) {
#pragma unroll
    for (int pass = 0; pass < CN * 7 / 224; ++pass) {
      int o = pass * 224 + t;
      int m = o / 7, jc = o - m * 7;
      int n = node0 + m;
      if (n < N) {
        float a = sbc[jc];
        const float* hp = hs2 + m * 32;
#pragma unroll
        for (int k = 0; k < 32; ++k) a += hp[k] * sWc[k * 7 + jc];
        out[(size_t)n * 7 + jc] = a;
      }
    }
  }
}

extern "C" void kernel_launch(void* const* d_in, const int* in_sizes, int n_in,
                              void* d_out, int out_size, void* d_ws,
                              size_t ws_size, hipStream_t stream) {
  const float* x   = (const float*)d_in[0];
  const int* ei_t  = (const int*)d_in[1];
  const int* ei_i  = (const int*)d_in[2];
  const float* W1t = (const float*)d_in[3];
  const float* b1t = (const float*)d_in[4];
  const float* W1i = (const float*)d_in[5];
  const float* b1i = (const float*)d_in[6];
  const float* W1r = (const float*)d_in[7];
  const float* b1r = (const float*)d_in[8];
  const float* W2t = (const float*)d_in[9];
  const float* b2t = (const float*)d_in[10];
  const float* W2i = (const float*)d_in[11];
  const float* b2i = (const float*)d_in[12];
  const float* W2r = (const float*)d_in[13];
  const float* b2r = (const float*)d_in[14];
  const float* Wc  = (const float*)d_in[15];
  const float* bc  = (const float*)d_in[16];
  float* out = (float*)d_out;

  const int N  = in_sizes[0] / 6;
  const int E  = in_sizes[1] / 2;
  const int Ei = in_sizes[2] / 2;
  const int K  = (N + RN - 1) / RN;
  const int halfN = N >> 1;   // halves must fit ushort: N <= 131070

  float* aggT = (float*)d_ws;
  float* aggI = aggT + (size_t)N * 32;
  unsigned short* h1b = (unsigned short*)(aggI + (size_t)N * 32);
  unsigned short* xp  = h1b + (size_t)N * 32;
  int* curT   = (int*)(xp + (size_t)N * 8);
  int* curI   = curT + KMAX;
  int* startT = curI + KMAX;
  int* degT   = startT + N;
  int* midT   = degT + N;
  int* startI = midT + N;
  int* degI   = startI + N;
  int* midI   = degI + N;
  int* binT   = midI + N;
  int* binI   = binT + (size_t)K * CAP;
  unsigned short* csrT = (unsigned short*)(binI + (size_t)K * CAP);
  unsigned short* csrI = csrT + (size_t)K * CAP;

  const int gN8  = (N * 8 + BLK - 1) / BLK;
  const int gG1  = (N + GN1 - 1) / GN1;
  const int gG2  = (N * 4 + BLK - 1) / BLK;
  const int gC2  = (N + CN - 1) / CN;
  const int Emax = (E > Ei) ? E : Ei;
  const int gBin = (Emax + CHUNK - 1) / CHUNK;

  // ---- build ----
  k_prep<<<gN8, BLK, 0, stream>>>(x, xp, curT, curI, N, K);
  k_bin3<<<dim3(gBin, 2), BLK, 0, stream>>>(ei_t, E, curT, binT, ei_i, Ei,
                                            curI, binI, K);
  k_sortcsr2m<<<dim3(K, 2), 512, 0, stream>>>(binT, curT, csrT, startT, degT,
                                              midT, binI, curI, csrI, startI,
                                              degI, midI, N, halfN);

  // ---- Layer 1 (fused gather+transform -> bf16 h1, LDS csr staging) ----
  k_g1c1<<<gG1, BLK, 0, stream>>>(xp, x, startT, degT, midT, csrT, startI,
                                  degI, midI, csrI, W1t, b1t, W1i, b1i, W1r,
                                  b1r, h1b, N, halfN);

  // ---- Layer 2 (src-half phased gather, then combine v4 + cls) ----
  k_gather2<<<dim3(gG2, 2), BLK, 0, stream>>>(h1b, startT, degT, midT, csrT,
                                              startI, degI, midI, csrI, aggT,
                                              aggI, N, halfN);
  k_combine2cls<<<gC2, BLK, 0, stream>>>(aggT, aggI, h1b, degT, degI, W2t,
                                         b2t, W2i, b2i, W2r, b2r, Wc, bc, out,
                                         N);
}

// Round 14
// 234.278 us; speedup vs baseline: 1.3464x; 1.0064x over previous
//
#include <hip/hip_runtime.h>

// Round 33: r32 config verbatim (measured best 235.8us) with ONE change:
// per-node CSR metadata packed into int4 meta[n] = {start, deg, mid, 0}.
// All consumers (g1c1: 8 thr/node, gather2: 4 thr/node x 2 etypes, combine)
// previously issued 3 scattered 4B loads per (node,etype); now 1x 16B load.
// Same 3-loads->1 transform that won r26. sortcsr writes the packed quad.
// No sync/layout/occupancy changes.
//
// ws: aggT aggI [N*32] f32 | h1b[N*32] xp[N*8] bf16 | curT curI |
//     metaT metaI [N] int4 | binT binI [K*CAP] int | csrT csrI [K*CAP] u16

#define BLK 256
#define RN 512            // nodes per bucket
#define KMAX 256          // max buckets (N <= 131072)
#define CAP 11264         // bucket capacity (mean 10204, +10 sigma)
#define CHUNK 4096        // edges per bin3 block
#define EPT 16            // edges per thread in bin3 (CHUNK/BLK)
#define BPT 22            // bin entries per thread in sortcsr (CAP/512)
#define CSRC 2048         // per-etype LDS csr cap in g1c1

typedef unsigned short us8 __attribute__((ext_vector_type(8)));

__device__ inline unsigned short f2bf(float f) {
  unsigned u = __float_as_uint(f);
  return (unsigned short)((u + 0x7FFFu + ((u >> 16) & 1u)) >> 16);
}
__device__ inline float bf2f(unsigned short h) {
  return __uint_as_float(((unsigned)h) << 16);
}

// ---------------- prep: x -> bf16 padded rows; init bucket cursors ----------
__global__ __launch_bounds__(BLK) void k_prep(const float* __restrict__ x,
                                              unsigned short* __restrict__ xp,
                                              int* __restrict__ curT,
                                              int* __restrict__ curI, int N,
                                              int K) {
  int gid = blockIdx.x * BLK + threadIdx.x;
  if (gid < K) {
    curT[gid] = gid * CAP;
    curI[gid] = gid * CAP;
  }
  if (gid >= N * 8) return;
  int n = gid >> 3, c = gid & 7;
  xp[gid] = (c < 6) ? f2bf(x[n * 6 + c]) : (unsigned short)0;
}

// ---------------- bin: LDS-staged local sort, register-cached edges --------
__global__ __launch_bounds__(BLK) void k_bin3(
    const int* __restrict__ eiT, int ET, int* __restrict__ curT,
    int* __restrict__ binT, const int* __restrict__ eiI, int EI,
    int* __restrict__ curI, int* __restrict__ binI, int K) {
  const int* ei = blockIdx.y ? eiI : eiT;
  int E = blockIdx.y ? EI : ET;
  int* gcur = blockIdx.y ? curI : curT;
  int* binned = blockIdx.y ? binI : binT;
  int cs = blockIdx.x * CHUNK;
  if (cs >= E) return;
  int ce = min(E, cs + CHUNK);
  int cnt = ce - cs;
  __shared__ int ebuf[CHUNK];
  __shared__ unsigned char bbuf[CHUNK];
  __shared__ int hist[KMAX], cur[KMAX], gdelta[KMAX], s[KMAX];
  int t = threadIdx.x;
  hist[t] = 0;
  __syncthreads();
  int rs[EPT], rd[EPT];
#pragma unroll
  for (int i = 0; i < EPT; ++i) {
    int e = cs + t + i * BLK;
    if (e < ce) {
      rs[i] = ei[e];
      rd[i] = ei[E + e];
      atomicAdd(&hist[rd[i] >> 9], 1);
    }
  }
  __syncthreads();
  int v = hist[t];
  s[t] = v;
  __syncthreads();
  for (int off = 1; off < KMAX; off <<= 1) {
    int x = (t >= off) ? s[t - off] : 0;
    __syncthreads();
    s[t] += x;
    __syncthreads();
  }
  int excl = s[t] - v;
  cur[t] = excl;
  if (t < K) gdelta[t] = atomicAdd(&gcur[t], v) - excl;
  __syncthreads();
#pragma unroll
  for (int i = 0; i < EPT; ++i) {
    int e = cs + t + i * BLK;
    if (e < ce) {
      int src = rs[i];
      int d = rd[i];
      int b = d >> 9;
      int slot = atomicAdd(&cur[b], 1);
      ebuf[slot] = (src << 9) | (d & 511);
      bbuf[slot] = (unsigned char)b;
    }
  }
  __syncthreads();
  for (int i = t; i < cnt; i += BLK) {
    int b = bbuf[i];
    __builtin_nontemporal_store(ebuf[i], &binned[i + gdelta[b]]);
  }
}

// per-bucket counting sort, (node, src-half) keys -> u16 csr + int4 meta
// bin entries register-cached across passes; scatter into LDS; coalesced out.
__global__ __launch_bounds__(512) void k_sortcsr2m(
    const int* __restrict__ binT, const int* __restrict__ curT,
    unsigned short* __restrict__ csrT, int4* __restrict__ metaT,
    const int* __restrict__ binI, const int* __restrict__ curI,
    unsigned short* __restrict__ csrI, int4* __restrict__ metaI, int N,
    int halfN) {
  const int* bin = blockIdx.y ? binI : binT;
  const int* cur = blockIdx.y ? curI : curT;
  unsigned short* csr = blockIdx.y ? csrI : csrT;
  int4* meta = blockIdx.y ? metaI : metaT;
  __shared__ int h[2 * RN], s[RN], c2[2 * RN];
  __shared__ unsigned short lcsr[CAP];
  int t = threadIdx.x, b = blockIdx.x;
  int e0 = b * CAP;
  int cnt = min(cur[b] - e0, CAP);
  h[t] = 0;
  h[t + RN] = 0;
  __syncthreads();
  int rp[BPT];
#pragma unroll
  for (int it = 0; it < BPT; ++it) {
    int i = t + it * 512;
    if (i < cnt) {
      int p = bin[e0 + i];
      rp[it] = p;
      int key = ((p & 511) << 1) | ((p >> 9) >= halfN ? 1 : 0);
      atomicAdd(&h[key], 1);
    }
  }
  __syncthreads();
  int lo = h[2 * t], hi = h[2 * t + 1];
  int pair = lo + hi;
  s[t] = pair;
  __syncthreads();
  for (int off = 1; off < 512; off <<= 1) {
    int v = (t >= off) ? s[t - off] : 0;
    __syncthreads();
    s[t] += v;
    __syncthreads();
  }
  int excl = s[t] - pair;
  c2[2 * t] = excl;
  c2[2 * t + 1] = excl + lo;
  int n = b * RN + t;
  if (n < N) meta[n] = make_int4(e0 + excl, pair, e0 + excl + lo, 0);
  __syncthreads();
#pragma unroll
  for (int it = 0; it < BPT; ++it) {
    int i = t + it * 512;
    if (i < cnt) {
      int p = rp[it];
      int src = p >> 9;
      int hiFlag = (src >= halfN) ? 1 : 0;
      int key = ((p & 511) << 1) | hiFlag;
      int pos = atomicAdd(&c2[key], 1);
      lcsr[pos] = (unsigned short)(src - hiFlag * halfN);
    }
  }
  __syncthreads();
  // coalesced write-out (e0*2 bytes is 4B-aligned since CAP is even)
  unsigned int* dst = (unsigned int*)(csr + e0);
  const unsigned int* srcp = (const unsigned int*)lcsr;
  int cnt2 = cnt >> 1;
  for (int i = t; i < cnt2; i += 512) dst[i] = srcp[i];
  if (t == 0 && (cnt & 1)) csr[e0 + cnt - 1] = lcsr[cnt - 1];
}

// ------- fused layer 1: 8 thr/node (etype x src-half x edge-parity),
//         LDS-staged csr segments, full 16B row loads, int4 meta ----------
#define GN1 32
__global__ __launch_bounds__(BLK) void k_g1c1(
    const unsigned short* __restrict__ xp, const float* __restrict__ x,
    const int4* __restrict__ metaT, const unsigned short* __restrict__ csrT,
    const int4* __restrict__ metaI, const unsigned short* __restrict__ csrI,
    const float* __restrict__ Wt, const float* __restrict__ bt,
    const float* __restrict__ Wi, const float* __restrict__ bi,
    const float* __restrict__ Wr, const float* __restrict__ br,
    unsigned short* __restrict__ h1b, int N, int halfN) {
  __shared__ float sGT[GN1 * 32], sGI[GN1 * 32], sx[GN1 * 6];
  __shared__ float sWt[192], sWi[192], sWr[192], sb[96];
  __shared__ float sdT[GN1], sdI[GN1];
  __shared__ unsigned short lcT[CSRC], lcI[CSRC];
  __shared__ int sm[4];
  int t = threadIdx.x, b = blockIdx.x;
  if (t < 192) { sWt[t] = Wt[t]; sWi[t] = Wi[t]; sWr[t] = Wr[t]; }
  if (t < 32) { sb[t] = bt[t]; sb[32 + t] = bi[t]; sb[64 + t] = br[t]; }
  if (t < GN1 * 6) {
    int g = b * GN1 * 6 + t;
    sx[t] = (g < N * 6) ? x[g] : 0.0f;
  }
  int n0 = b * GN1;
  if (t == 0) {
    // block's 32 nodes are bucket-contiguous: csr segment per etype is one
    // contiguous run [meta[n0].x, meta[nL].x + meta[nL].y)
    int nL = min(n0 + GN1, N) - 1;
    int4 mT0 = metaT[n0], mTL = metaT[nL];
    sm[0] = mT0.x;
    sm[1] = mTL.x + mTL.y - mT0.x;
    int4 mI0 = metaI[n0], mIL = metaI[nL];
    sm[2] = mI0.x;
    sm[3] = mIL.x + mIL.y - mI0.x;
  }
  __syncthreads();
  int baseT = sm[0], lenT = sm[1], baseI = sm[2], lenI = sm[3];
  {
    int lt = min(lenT, CSRC);
    for (int i = t; i < lt; i += BLK) lcT[i] = csrT[baseT + i];
    int li = min(lenI, CSRC);
    for (int i = t; i < li; i += BLK) lcI[i] = csrI[baseI + i];
  }
  __syncthreads();
  int nl = t >> 3, et = (t >> 2) & 1, half = (t >> 1) & 1, par = t & 1;
  int n = n0 + nl;
  float a[8] = {0.f, 0.f, 0.f, 0.f, 0.f, 0.f, 0.f, 0.f};
  int d = 0;
  if (n < N) {
    const int4* metaA = et ? metaI : metaT;
    int baseA = et ? baseI : baseT;
    int lenA = et ? lenI : lenT;
    const unsigned short* csrp =
        (lenA <= CSRC) ? (const unsigned short*)(et ? lcI : lcT)
                       : ((et ? csrI : csrT) + baseA);
    int4 mv = metaA[n];
    int s0 = mv.x;
    d = mv.y;
    int m = mv.z;
    int i0 = (half ? m : s0) - baseA;
    int i1 = (half ? (s0 + d) : m) - baseA;
    const unsigned short* tab = xp + (half ? (size_t)halfN * 8 : 0);
    int i = i0 + par;
    for (; i + 6 < i1; i += 8) {
      int r0 = csrp[i], r1 = csrp[i + 2], r2 = csrp[i + 4], r3 = csrp[i + 6];
      us8 v0 = *(const us8*)(tab + (size_t)r0 * 8);
      us8 v1 = *(const us8*)(tab + (size_t)r1 * 8);
      us8 v2 = *(const us8*)(tab + (size_t)r2 * 8);
      us8 v3 = *(const us8*)(tab + (size_t)r3 * 8);
#pragma unroll
      for (int k = 0; k < 8; ++k)
        a[k] += (bf2f(v0[k]) + bf2f(v1[k])) + (bf2f(v2[k]) + bf2f(v3[k]));
    }
    for (; i < i1; i += 2) {
      int r0 = csrp[i];
      us8 v0 = *(const us8*)(tab + (size_t)r0 * 8);
#pragma unroll
      for (int k = 0; k < 8; ++k) a[k] += bf2f(v0[k]);
    }
  }
  // slot = half*2 + par; 4 slots x 8ch = 32 floats per (node, etype)
  float* dst = (et ? sGI : sGT) + nl * 32 + (half * 2 + par) * 8;
#pragma unroll
  for (int k = 0; k < 8; ++k) dst[k] = a[k];
  if (half == 0 && par == 0) {
    if (et) sdI[nl] = (float)d;
    else    sdT[nl] = (float)d;
  }
  __syncthreads();
  for (int idx = t; idx < GN1 * 32; idx += BLK) {
    int m = idx >> 5, j = idx & 31;
    int nn = n0 + m;
    if (nn >= N) break;
    float fdT = sdT[m], fdI = sdI[m];
    float invI = 1.0f / fmaxf(fdI, 1.0f);
    float gate = (fdI > 0.0f) ? 1.0f : 0.0f;
    float acc = fdT * sb[j] + gate * sb[32 + j] + sb[64 + j];
#pragma unroll
    for (int k = 0; k < 6; ++k) {
      float gT = sGT[m * 32 + k] + sGT[m * 32 + 8 + k] +
                 sGT[m * 32 + 16 + k] + sGT[m * 32 + 24 + k];
      float gI = sGI[m * 32 + k] + sGI[m * 32 + 8 + k] +
                 sGI[m * 32 + 16 + k] + sGI[m * 32 + 24 + k];
      acc += gT * sWt[k * 32 + j];
      acc += gI * invI * sWi[k * 32 + j];
      acc += sx[m * 6 + k] * sWr[k * 32 + j];
    }
    h1b[(size_t)nn * 32 + j] = f2bf(fmaxf(acc, 0.0f));
  }
}

// ---------------- layer-2 gather helper: unroll-4, 16B bf16 loads ----------
__device__ inline void accum8(const unsigned short* __restrict__ tab,
                              const unsigned short* __restrict__ csr, int i0,
                              int i1, float* a) {
  int i = i0;
  for (; i + 4 <= i1; i += 4) {
    int r0 = csr[i], r1 = csr[i + 1], r2 = csr[i + 2], r3 = csr[i + 3];
    us8 v0 = *(const us8*)(tab + (size_t)r0 * 32);
    us8 v1 = *(const us8*)(tab + (size_t)r1 * 32);
    us8 v2 = *(const us8*)(tab + (size_t)r2 * 32);
    us8 v3 = *(const us8*)(tab + (size_t)r3 * 32);
#pragma unroll
    for (int k = 0; k < 8; ++k)
      a[k] += (bf2f(v0[k]) + bf2f(v1[k])) + (bf2f(v2[k]) + bf2f(v3[k]));
  }
  for (; i < i1; ++i) {
    int r0 = csr[i];
    us8 v0 = *(const us8*)(tab + (size_t)r0 * 32);
#pragma unroll
    for (int k = 0; k < 8; ++k) a[k] += bf2f(v0[k]);
  }
}

// --- layer-2 gather: 4 thr/node (chan-quarter), src-half phased, int4 meta -
__global__ __launch_bounds__(BLK) void k_gather2(
    const unsigned short* __restrict__ h1b, const int4* __restrict__ metaT,
    const unsigned short* __restrict__ csrT, const int4* __restrict__ metaI,
    const unsigned short* __restrict__ csrI, float* __restrict__ aggT,
    float* __restrict__ aggI, int N, int halfN) {
  const int4* meta = blockIdx.y ? metaI : metaT;
  const unsigned short* csr = blockIdx.y ? csrI : csrT;
  float* agg = blockIdx.y ? aggI : aggT;
  int gid = blockIdx.x * BLK + threadIdx.x;
  int n = gid >> 2;
  if (n >= N) return;
  int c8 = (gid & 3) * 8;
  float a[8] = {0.f, 0.f, 0.f, 0.f, 0.f, 0.f, 0.f, 0.f};
  int4 mv = meta[n];
  int s0 = mv.x, d = mv.y, m = mv.z;
  // phase 0: src < N/2 (lower table half L2-resident chip-wide), then phase 1
  accum8(h1b + c8, csr, s0, m, a);
  accum8(h1b + (size_t)halfN * 32 + c8, csr, m, s0 + d, a);
  float* p = agg + (size_t)n * 32 + c8;
#pragma unroll
  for (int k = 0; k < 8; ++k) __builtin_nontemporal_store(a[k], p + k);
}

// ------- combine2 + classifier v4: r17 staging, PHASE-WISE reg weights -----
#define CN 64
__global__ __launch_bounds__(BLK) void k_combine2cls(
    const float* __restrict__ aggT, const float* __restrict__ aggI,
    const unsigned short* __restrict__ h1b, const int4* __restrict__ metaT,
    const int4* __restrict__ metaI, const float* __restrict__ Wt,
    const float* __restrict__ bt, const float* __restrict__ Wi,
    const float* __restrict__ bi, const float* __restrict__ Wr,
    const float* __restrict__ br, const float* __restrict__ Wc,
    const float* __restrict__ bc, float* __restrict__ out, int N) {
  __shared__ float hTs[CN * 32], hIs[CN * 32], hRs[CN * 32], hs2[CN * 32];
  __shared__ float sWc[224], sbc[7], sb[96];
  __shared__ float sdT[CN], sdI[CN];
  int t = threadIdx.x;
  int j = t & 31, ln = t >> 5;
  int node0 = blockIdx.x * CN;
  size_t gbase = (size_t)node0 * 32;
  {
    const float4* sT = (const float4*)(aggT + gbase);
    const float4* sI = (const float4*)(aggI + gbase);
    ((float4*)hTs)[t] = sT[t];
    ((float4*)hTs)[t + 256] = sT[t + 256];
    ((float4*)hIs)[t] = sI[t];
    ((float4*)hIs)[t + 256] = sI[t + 256];
    us8 v = ((const us8*)(h1b + gbase))[t];
    float4 lo = {bf2f(v[0]), bf2f(v[1]), bf2f(v[2]), bf2f(v[3])};
    float4 hi = {bf2f(v[4]), bf2f(v[5]), bf2f(v[6]), bf2f(v[7])};
    ((float4*)hRs)[2 * t] = lo;
    ((float4*)hRs)[2 * t + 1] = hi;
  }
  if (t < 224) sWc[t] = Wc[t];
  if (t < 7) sbc[t] = bc[t];
  if (t < 32) { sb[t] = bt[t]; sb[32 + t] = bi[t]; sb[64 + t] = br[t]; }
  if (t < CN) {
    int n = node0 + t;
    sdT[t] = (n < N) ? (float)metaT[n].y : 0.f;
    sdI[t] = (n < N) ? (float)metaI[n].y : 0.f;
  }
  float w[32];
  __syncthreads();
  // ---- phase T: base + aggT @ Wt ----
#pragma unroll
  for (int k = 0; k < 32; ++k) w[k] = Wt[k * 32 + j];
#pragma unroll
  for (int it = 0; it < CN / 8; ++it) {
    int li = it * 8 + ln;
    float dT = sdT[li], dI = sdI[li];
    float gate = (dI > 0.0f) ? 1.0f : 0.0f;
    float aT = 0.f;
    const float4* h4 = (const float4*)(hTs + li * 32);
#pragma unroll
    for (int kk = 0; kk < 8; ++kk) {
      float4 a = h4[kk];
      aT += a.x * w[kk * 4 + 0] + a.y * w[kk * 4 + 1] +
            a.z * w[kk * 4 + 2] + a.w * w[kk * 4 + 3];
    }
    hs2[li * 32 + j] = dT * sb[j] + gate * sb[32 + j] + sb[64 + j] + aT;
  }
  // ---- phase I: += invI * (aggI @ Wi) ----
#pragma unroll
  for (int k = 0; k < 32; ++k) w[k] = Wi[k * 32 + j];
#pragma unroll
  for (int it = 0; it < CN / 8; ++it) {
    int li = it * 8 + ln;
    float invI = 1.0f / fmaxf(sdI[li], 1.0f);
    float aI = 0.f;
    const float4* h4 = (const float4*)(hIs + li * 32);
#pragma unroll
    for (int kk = 0; kk < 8; ++kk) {
      float4 a = h4[kk];
      aI += a.x * w[kk * 4 + 0] + a.y * w[kk * 4 + 1] +
            a.z * w[kk * 4 + 2] + a.w * w[kk * 4 + 3];
    }
    hs2[li * 32 + j] += invI * aI;
  }
  // ---- phase R: += h1 @ Wr, then ReLU ----
#pragma unroll
  for (int k = 0; k < 32; ++k) w[k] = Wr[k * 32 + j];
#pragma unroll
  for (int it = 0; it < CN / 8; ++it) {
    int li = it * 8 + ln;
    float aR = 0.f;
    const float4* h4 = (const float4*)(hRs + li * 32);
#pragma unroll
    for (int kk = 0; kk < 8; ++kk) {
      float4 a = h4[kk];
      aR += a.x * w[kk * 4 + 0] + a.y * w[kk * 4 + 1] +
            a.z * w[kk * 4 + 2] + a.w * w[kk * 4 + 3];
    }
    hs2[li * 32 + j] = fmaxf(hs2[li * 32 + j] + aR, 0.0f);
  }
  __syncthreads();
  if (t < 224) {
#pragma unroll
    for (int pass = 0; pass < CN * 7 / 224; ++pass) {
      int o = pass * 224 + t;
      int m = o / 7, jc = o - m * 7;
      int n = node0 + m;
      if (n < N) {
        float a = sbc[jc];
        const float* hp = hs2 + m * 32;
#pragma unroll
        for (int k = 0; k < 32; ++k) a += hp[k] * sWc[k * 7 + jc];
        out[(size_t)n * 7 + jc] = a;
      }
    }
  }
}

extern "C" void kernel_launch(void* const* d_in, const int* in_sizes, int n_in,
                              void* d_out, int out_size, void* d_ws,
                              size_t ws_size, hipStream_t stream) {
  const float* x   = (const float*)d_in[0];
  const int* ei_t  = (const int*)d_in[1];
  const int* ei_i  = (const int*)d_in[2];
  const float* W1t = (const float*)d_in[3];
  const float* b1t = (const float*)d_in[4];
  const float* W1i = (const float*)d_in[5];
  const float* b1i = (const float*)d_in[6];
  const float* W1r = (const float*)d_in[7];
  const float* b1r = (const float*)d_in[8];
  const float* W2t = (const float*)d_in[9];
  const float* b2t = (const float*)d_in[10];
  const float* W2i = (const float*)d_in[11];
  const float* b2i = (const float*)d_in[12];
  const float* W2r = (const float*)d_in[13];
  const float* b2r = (const float*)d_in[14];
  const float* Wc  = (const float*)d_in[15];
  const float* bc  = (const float*)d_in[16];
  float* out = (float*)d_out;

  const int N  = in_sizes[0] / 6;
  const int E  = in_sizes[1] / 2;
  const int Ei = in_sizes[2] / 2;
  const int K  = (N + RN - 1) / RN;
  const int halfN = N >> 1;   // halves must fit ushort: N <= 131070

  float* aggT = (float*)d_ws;
  float* aggI = aggT + (size_t)N * 32;
  unsigned short* h1b = (unsigned short*)(aggI + (size_t)N * 32);
  unsigned short* xp  = h1b + (size_t)N * 32;
  int* curT   = (int*)(xp + (size_t)N * 8);
  int* curI   = curT + KMAX;
  int4* metaT = (int4*)(curI + KMAX);
  int4* metaI = metaT + N;
  int* binT   = (int*)(metaI + N);
  int* binI   = binT + (size_t)K * CAP;
  unsigned short* csrT = (unsigned short*)(binI + (size_t)K * CAP);
  unsigned short* csrI = csrT + (size_t)K * CAP;

  const int gN8  = (N * 8 + BLK - 1) / BLK;
  const int gG1  = (N + GN1 - 1) / GN1;
  const int gG2  = (N * 4 + BLK - 1) / BLK;
  const int gC2  = (N + CN - 1) / CN;
  const int Emax = (E > Ei) ? E : Ei;
  const int gBin = (Emax + CHUNK - 1) / CHUNK;

  // ---- build ----
  k_prep<<<gN8, BLK, 0, stream>>>(x, xp, curT, curI, N, K);
  k_bin3<<<dim3(gBin, 2), BLK, 0, stream>>>(ei_t, E, curT, binT, ei_i, Ei,
                                            curI, binI, K);
  k_sortcsr2m<<<dim3(K, 2), 512, 0, stream>>>(binT, curT, csrT, metaT, binI,
                                              curI, csrI, metaI, N, halfN);

  // ---- Layer 1 (fused gather+transform -> bf16 h1, LDS csr staging) ----
  k_g1c1<<<gG1, BLK, 0, stream>>>(xp, x, metaT, csrT, metaI, csrI, W1t, b1t,
                                  W1i, b1i, W1r, b1r, h1b, N, halfN);

  // ---- Layer 2 (src-half phased gather, then combine v4 + cls) ----
  k_gather2<<<dim3(gG2, 2), BLK, 0, stream>>>(h1b, metaT, csrT, metaI, csrI,
                                              aggT, aggI, N, halfN);
  k_combine2cls<<<gC2, BLK, 0, stream>>>(aggT, aggI, h1b, metaT, metaI, W2t,
                                         b2t, W2i, b2i, W2r, b2r, Wc, bc, out,
                                         N);
}

// Round 15
// 227.989 us; speedup vs baseline: 1.3836x; 1.0276x over previous
//
#include <hip/hip_runtime.h>

// Round 34: r33 config verbatim (measured best 234.3us) with ONE change:
// k_bin3 chunk geometry CHUNK 4096->8192, BLK 256->512 (EPT stays 16).
// Halves per-edge scan/barrier/gdelta-atomic overhead; doubles binned[]
// write runs (21->42 entries, ~84B->~168B => ~3->~1.5 segments per wave
// store). LDS 20->44KB = 24 waves/CU (was 32) -- still ample for a
// streaming kernel. Everything else untouched.
//
// ws: aggT aggI [N*32] f32 | h1b[N*32] xp[N*8] bf16 | curT curI |
//     metaT metaI [N] int4 | binT binI [K*CAP] int | csrT csrI [K*CAP] u16

#define BLK 256
#define RN 512            // nodes per bucket
#define KMAX 256          // max buckets (N <= 131072)
#define CAP 11264         // bucket capacity (mean 10204, +10 sigma)
#define CHUNK 8192        // edges per bin3 block
#define BBLK 512          // bin3 block size
#define EPT 16            // edges per thread in bin3 (CHUNK/BBLK)
#define BPT 22            // bin entries per thread in sortcsr (CAP/512)
#define CSRC 2048         // per-etype LDS csr cap in g1c1

typedef unsigned short us8 __attribute__((ext_vector_type(8)));

__device__ inline unsigned short f2bf(float f) {
  unsigned u = __float_as_uint(f);
  return (unsigned short)((u + 0x7FFFu + ((u >> 16) & 1u)) >> 16);
}
__device__ inline float bf2f(unsigned short h) {
  return __uint_as_float(((unsigned)h) << 16);
}

// ---------------- prep: x -> bf16 padded rows; init bucket cursors ----------
__global__ __launch_bounds__(BLK) void k_prep(const float* __restrict__ x,
                                              unsigned short* __restrict__ xp,
                                              int* __restrict__ curT,
                                              int* __restrict__ curI, int N,
                                              int K) {
  int gid = blockIdx.x * BLK + threadIdx.x;
  if (gid < K) {
    curT[gid] = gid * CAP;
    curI[gid] = gid * CAP;
  }
  if (gid >= N * 8) return;
  int n = gid >> 3, c = gid & 7;
  xp[gid] = (c < 6) ? f2bf(x[n * 6 + c]) : (unsigned short)0;
}

// ---------------- bin: LDS-staged local sort, register-cached edges --------
__global__ __launch_bounds__(BBLK) void k_bin3(
    const int* __restrict__ eiT, int ET, int* __restrict__ curT,
    int* __restrict__ binT, const int* __restrict__ eiI, int EI,
    int* __restrict__ curI, int* __restrict__ binI, int K) {
  const int* ei = blockIdx.y ? eiI : eiT;
  int E = blockIdx.y ? EI : ET;
  int* gcur = blockIdx.y ? curI : curT;
  int* binned = blockIdx.y ? binI : binT;
  int cs = blockIdx.x * CHUNK;
  if (cs >= E) return;
  int ce = min(E, cs + CHUNK);
  int cnt = ce - cs;
  __shared__ int ebuf[CHUNK];
  __shared__ unsigned char bbuf[CHUNK];
  __shared__ int hist[KMAX], cur[KMAX], gdelta[KMAX], s[KMAX];
  int t = threadIdx.x;
  if (t < KMAX) hist[t] = 0;
  __syncthreads();
  int rs[EPT], rd[EPT];
#pragma unroll
  for (int i = 0; i < EPT; ++i) {
    int e = cs + t + i * BBLK;
    if (e < ce) {
      rs[i] = ei[e];
      rd[i] = ei[E + e];
      atomicAdd(&hist[rd[i] >> 9], 1);
    }
  }
  __syncthreads();
  int v = 0;
  if (t < KMAX) {
    v = hist[t];
    s[t] = v;
  }
  __syncthreads();
  for (int off = 1; off < KMAX; off <<= 1) {
    int x = (t >= off && t < KMAX) ? s[t - off] : 0;
    __syncthreads();
    if (t < KMAX) s[t] += x;
    __syncthreads();
  }
  if (t < KMAX) {
    int excl = s[t] - v;
    cur[t] = excl;
    if (t < K) gdelta[t] = atomicAdd(&gcur[t], v) - excl;
  }
  __syncthreads();
#pragma unroll
  for (int i = 0; i < EPT; ++i) {
    int e = cs + t + i * BBLK;
    if (e < ce) {
      int src = rs[i];
      int d = rd[i];
      int b = d >> 9;
      int slot = atomicAdd(&cur[b], 1);
      ebuf[slot] = (src << 9) | (d & 511);
      bbuf[slot] = (unsigned char)b;
    }
  }
  __syncthreads();
  for (int i = t; i < cnt; i += BBLK) {
    int b = bbuf[i];
    __builtin_nontemporal_store(ebuf[i], &binned[i + gdelta[b]]);
  }
}

// per-bucket counting sort, (node, src-half) keys -> u16 csr + int4 meta
// bin entries register-cached across passes; scatter into LDS; coalesced out.
__global__ __launch_bounds__(512) void k_sortcsr2m(
    const int* __restrict__ binT, const int* __restrict__ curT,
    unsigned short* __restrict__ csrT, int4* __restrict__ metaT,
    const int* __restrict__ binI, const int* __restrict__ curI,
    unsigned short* __restrict__ csrI, int4* __restrict__ metaI, int N,
    int halfN) {
  const int* bin = blockIdx.y ? binI : binT;
  const int* cur = blockIdx.y ? curI : curT;
  unsigned short* csr = blockIdx.y ? csrI : csrT;
  int4* meta = blockIdx.y ? metaI : metaT;
  __shared__ int h[2 * RN], s[RN], c2[2 * RN];
  __shared__ unsigned short lcsr[CAP];
  int t = threadIdx.x, b = blockIdx.x;
  int e0 = b * CAP;
  int cnt = min(cur[b] - e0, CAP);
  h[t] = 0;
  h[t + RN] = 0;
  __syncthreads();
  int rp[BPT];
#pragma unroll
  for (int it = 0; it < BPT; ++it) {
    int i = t + it * 512;
    if (i < cnt) {
      int p = bin[e0 + i];
      rp[it] = p;
      int key = ((p & 511) << 1) | ((p >> 9) >= halfN ? 1 : 0);
      atomicAdd(&h[key], 1);
    }
  }
  __syncthreads();
  int lo = h[2 * t], hi = h[2 * t + 1];
  int pair = lo + hi;
  s[t] = pair;
  __syncthreads();
  for (int off = 1; off < 512; off <<= 1) {
    int v = (t >= off) ? s[t - off] : 0;
    __syncthreads();
    s[t] += v;
    __syncthreads();
  }
  int excl = s[t] - pair;
  c2[2 * t] = excl;
  c2[2 * t + 1] = excl + lo;
  int n = b * RN + t;
  if (n < N) meta[n] = make_int4(e0 + excl, pair, e0 + excl + lo, 0);
  __syncthreads();
#pragma unroll
  for (int it = 0; it < BPT; ++it) {
    int i = t + it * 512;
    if (i < cnt) {
      int p = rp[it];
      int src = p >> 9;
      int hiFlag = (src >= halfN) ? 1 : 0;
      int key = ((p & 511) << 1) | hiFlag;
      int pos = atomicAdd(&c2[key], 1);
      lcsr[pos] = (unsigned short)(src - hiFlag * halfN);
    }
  }
  __syncthreads();
  // coalesced write-out (e0*2 bytes is 4B-aligned since CAP is even)
  unsigned int* dst = (unsigned int*)(csr + e0);
  const unsigned int* srcp = (const unsigned int*)lcsr;
  int cnt2 = cnt >> 1;
  for (int i = t; i < cnt2; i += 512) dst[i] = srcp[i];
  if (t == 0 && (cnt & 1)) csr[e0 + cnt - 1] = lcsr[cnt - 1];
}

// ------- fused layer 1: 8 thr/node (etype x src-half x edge-parity),
//         LDS-staged csr segments, full 16B row loads, int4 meta ----------
#define GN1 32
__global__ __launch_bounds__(BLK) void k_g1c1(
    const unsigned short* __restrict__ xp, const float* __restrict__ x,
    const int4* __restrict__ metaT, const unsigned short* __restrict__ csrT,
    const int4* __restrict__ metaI, const unsigned short* __restrict__ csrI,
    const float* __restrict__ Wt, const float* __restrict__ bt,
    const float* __restrict__ Wi, const float* __restrict__ bi,
    const float* __restrict__ Wr, const float* __restrict__ br,
    unsigned short* __restrict__ h1b, int N, int halfN) {
  __shared__ float sGT[GN1 * 32], sGI[GN1 * 32], sx[GN1 * 6];
  __shared__ float sWt[192], sWi[192], sWr[192], sb[96];
  __shared__ float sdT[GN1], sdI[GN1];
  __shared__ unsigned short lcT[CSRC], lcI[CSRC];
  __shared__ int sm[4];
  int t = threadIdx.x, b = blockIdx.x;
  if (t < 192) { sWt[t] = Wt[t]; sWi[t] = Wi[t]; sWr[t] = Wr[t]; }
  if (t < 32) { sb[t] = bt[t]; sb[32 + t] = bi[t]; sb[64 + t] = br[t]; }
  if (t < GN1 * 6) {
    int g = b * GN1 * 6 + t;
    sx[t] = (g < N * 6) ? x[g] : 0.0f;
  }
  int n0 = b * GN1;
  if (t == 0) {
    // block's 32 nodes are bucket-contiguous: csr segment per etype is one
    // contiguous run [meta[n0].x, meta[nL].x + meta[nL].y)
    int nL = min(n0 + GN1, N) - 1;
    int4 mT0 = metaT[n0], mTL = metaT[nL];
    sm[0] = mT0.x;
    sm[1] = mTL.x + mTL.y - mT0.x;
    int4 mI0 = metaI[n0], mIL = metaI[nL];
    sm[2] = mI0.x;
    sm[3] = mIL.x + mIL.y - mI0.x;
  }
  __syncthreads();
  int baseT = sm[0], lenT = sm[1], baseI = sm[2], lenI = sm[3];
  {
    int lt = min(lenT, CSRC);
    for (int i = t; i < lt; i += BLK) lcT[i] = csrT[baseT + i];
    int li = min(lenI, CSRC);
    for (int i = t; i < li; i += BLK) lcI[i] = csrI[baseI + i];
  }
  __syncthreads();
  int nl = t >> 3, et = (t >> 2) & 1, half = (t >> 1) & 1, par = t & 1;
  int n = n0 + nl;
  float a[8] = {0.f, 0.f, 0.f, 0.f, 0.f, 0.f, 0.f, 0.f};
  int d = 0;
  if (n < N) {
    const int4* metaA = et ? metaI : metaT;
    int baseA = et ? baseI : baseT;
    int lenA = et ? lenI : lenT;
    const unsigned short* csrp =
        (lenA <= CSRC) ? (const unsigned short*)(et ? lcI : lcT)
                       : ((et ? csrI : csrT) + baseA);
    int4 mv = metaA[n];
    int s0 = mv.x;
    d = mv.y;
    int m = mv.z;
    int i0 = (half ? m : s0) - baseA;
    int i1 = (half ? (s0 + d) : m) - baseA;
    const unsigned short* tab = xp + (half ? (size_t)halfN * 8 : 0);
    int i = i0 + par;
    for (; i + 6 < i1; i += 8) {
      int r0 = csrp[i], r1 = csrp[i + 2], r2 = csrp[i + 4], r3 = csrp[i + 6];
      us8 v0 = *(const us8*)(tab + (size_t)r0 * 8);
      us8 v1 = *(const us8*)(tab + (size_t)r1 * 8);
      us8 v2 = *(const us8*)(tab + (size_t)r2 * 8);
      us8 v3 = *(const us8*)(tab + (size_t)r3 * 8);
#pragma unroll
      for (int k = 0; k < 8; ++k)
        a[k] += (bf2f(v0[k]) + bf2f(v1[k])) + (bf2f(v2[k]) + bf2f(v3[k]));
    }
    for (; i < i1; i += 2) {
      int r0 = csrp[i];
      us8 v0 = *(const us8*)(tab + (size_t)r0 * 8);
#pragma unroll
      for (int k = 0; k < 8; ++k) a[k] += bf2f(v0[k]);
    }
  }
  // slot = half*2 + par; 4 slots x 8ch = 32 floats per (node, etype)
  float* dst = (et ? sGI : sGT) + nl * 32 + (half * 2 + par) * 8;
#pragma unroll
  for (int k = 0; k < 8; ++k) dst[k] = a[k];
  if (half == 0 && par == 0) {
    if (et) sdI[nl] = (float)d;
    else    sdT[nl] = (float)d;
  }
  __syncthreads();
  for (int idx = t; idx < GN1 * 32; idx += BLK) {
    int m = idx >> 5, j = idx & 31;
    int nn = n0 + m;
    if (nn >= N) break;
    float fdT = sdT[m], fdI = sdI[m];
    float invI = 1.0f / fmaxf(fdI, 1.0f);
    float gate = (fdI > 0.0f) ? 1.0f : 0.0f;
    float acc = fdT * sb[j] + gate * sb[32 + j] + sb[64 + j];
#pragma unroll
    for (int k = 0; k < 6; ++k) {
      float gT = sGT[m * 32 + k] + sGT[m * 32 + 8 + k] +
                 sGT[m * 32 + 16 + k] + sGT[m * 32 + 24 + k];
      float gI = sGI[m * 32 + k] + sGI[m * 32 + 8 + k] +
                 sGI[m * 32 + 16 + k] + sGI[m * 32 + 24 + k];
      acc += gT * sWt[k * 32 + j];
      acc += gI * invI * sWi[k * 32 + j];
      acc += sx[m * 6 + k] * sWr[k * 32 + j];
    }
    h1b[(size_t)nn * 32 + j] = f2bf(fmaxf(acc, 0.0f));
  }
}

// ---------------- layer-2 gather helper: unroll-4, 16B bf16 loads ----------
__device__ inline void accum8(const unsigned short* __restrict__ tab,
                              const unsigned short* __restrict__ csr, int i0,
                              int i1, float* a) {
  int i = i0;
  for (; i + 4 <= i1; i += 4) {
    int r0 = csr[i], r1 = csr[i + 1], r2 = csr[i + 2], r3 = csr[i + 3];
    us8 v0 = *(const us8*)(tab + (size_t)r0 * 32);
    us8 v1 = *(const us8*)(tab + (size_t)r1 * 32);
    us8 v2 = *(const us8*)(tab + (size_t)r2 * 32);
    us8 v3 = *(const us8*)(tab + (size_t)r3 * 32);
#pragma unroll
    for (int k = 0; k < 8; ++k)
      a[k] += (bf2f(v0[k]) + bf2f(v1[k])) + (bf2f(v2[k]) + bf2f(v3[k]));
  }
  for (; i < i1; ++i) {
    int r0 = csr[i];
    us8 v0 = *(const us8*)(tab + (size_t)r0 * 32);
#pragma unroll
    for (int k = 0; k < 8; ++k) a[k] += bf2f(v0[k]);
  }
}

// --- layer-2 gather: 4 thr/node (chan-quarter), src-half phased, int4 meta -
__global__ __launch_bounds__(BLK) void k_gather2(
    const unsigned short* __restrict__ h1b, const int4* __restrict__ metaT,
    const unsigned short* __restrict__ csrT, const int4* __restrict__ metaI,
    const unsigned short* __restrict__ csrI, float* __restrict__ aggT,
    float* __restrict__ aggI, int N, int halfN) {
  const int4* meta = blockIdx.y ? metaI : metaT;
  const unsigned short* csr = blockIdx.y ? csrI : csrT;
  float* agg = blockIdx.y ? aggI : aggT;
  int gid = blockIdx.x * BLK + threadIdx.x;
  int n = gid >> 2;
  if (n >= N) return;
  int c8 = (gid & 3) * 8;
  float a[8] = {0.f, 0.f, 0.f, 0.f, 0.f, 0.f, 0.f, 0.f};
  int4 mv = meta[n];
  int s0 = mv.x, d = mv.y, m = mv.z;
  // phase 0: src < N/2 (lower table half L2-resident chip-wide), then phase 1
  accum8(h1b + c8, csr, s0, m, a);
  accum8(h1b + (size_t)halfN * 32 + c8, csr, m, s0 + d, a);
  float* p = agg + (size_t)n * 32 + c8;
#pragma unroll
  for (int k = 0; k < 8; ++k) __builtin_nontemporal_store(a[k], p + k);
}

// ------- combine2 + classifier v4: r17 staging, PHASE-WISE reg weights -----
#define CN 64
__global__ __launch_bounds__(BLK) void k_combine2cls(
    const float* __restrict__ aggT, const float* __restrict__ aggI,
    const unsigned short* __restrict__ h1b, const int4* __restrict__ metaT,
    const int4* __restrict__ metaI, const float* __restrict__ Wt,
    const float* __restrict__ bt, const float* __restrict__ Wi,
    const float* __restrict__ bi, const float* __restrict__ Wr,
    const float* __restrict__ br, const float* __restrict__ Wc,
    const float* __restrict__ bc, float* __restrict__ out, int N) {
  __shared__ float hTs[CN * 32], hIs[CN * 32], hRs[CN * 32], hs2[CN * 32];
  __shared__ float sWc[224], sbc[7], sb[96];
  __shared__ float sdT[CN], sdI[CN];
  int t = threadIdx.x;
  int j = t & 31, ln = t >> 5;
  int node0 = blockIdx.x * CN;
  size_t gbase = (size_t)node0 * 32;
  {
    const float4* sT = (const float4*)(aggT + gbase);
    const float4* sI = (const float4*)(aggI + gbase);
    ((float4*)hTs)[t] = sT[t];
    ((float4*)hTs)[t + 256] = sT[t + 256];
    ((float4*)hIs)[t] = sI[t];
    ((float4*)hIs)[t + 256] = sI[t + 256];
    us8 v = ((const us8*)(h1b + gbase))[t];
    float4 lo = {bf2f(v[0]), bf2f(v[1]), bf2f(v[2]), bf2f(v[3])};
    float4 hi = {bf2f(v[4]), bf2f(v[5]), bf2f(v[6]), bf2f(v[7])};
    ((float4*)hRs)[2 * t] = lo;
    ((float4*)hRs)[2 * t + 1] = hi;
  }
  if (t < 224) sWc[t] = Wc[t];
  if (t < 7) sbc[t] = bc[t];
  if (t < 32) { sb[t] = bt[t]; sb[32 + t] = bi[t]; sb[64 + t] = br[t]; }
  if (t < CN) {
    int n = node0 + t;
    sdT[t] = (n < N) ? (float)metaT[n].y : 0.f;
    sdI[t] = (n < N) ? (float)metaI[n].y : 0.f;
  }
  float w[32];
  __syncthreads();
  // ---- phase T: base + aggT @ Wt ----
#pragma unroll
  for (int k = 0; k < 32; ++k) w[k] = Wt[k * 32 + j];
#pragma unroll
  for (int it = 0; it < CN / 8; ++it) {
    int li = it * 8 + ln;
    float dT = sdT[li], dI = sdI[li];
    float gate = (dI > 0.0f) ? 1.0f : 0.0f;
    float aT = 0.f;
    const float4* h4 = (const float4*)(hTs + li * 32);
#pragma unroll
    for (int kk = 0; kk < 8; ++kk) {
      float4 a = h4[kk];
      aT += a.x * w[kk * 4 + 0] + a.y * w[kk * 4 + 1] +
            a.z * w[kk * 4 + 2] + a.w * w[kk * 4 + 3];
    }
    hs2[li * 32 + j] = dT * sb[j] + gate * sb[32 + j] + sb[64 + j] + aT;
  }
  // ---- phase I: += invI * (aggI @ Wi) ----
#pragma unroll
  for (int k = 0; k < 32; ++k) w[k] = Wi[k * 32 + j];
#pragma unroll
  for (int it = 0; it < CN / 8; ++it) {
    int li = it * 8 + ln;
    float invI = 1.0f / fmaxf(sdI[li], 1.0f);
    float aI = 0.f;
    const float4* h4 = (const float4*)(hIs + li * 32);
#pragma unroll
    for (int kk = 0; kk < 8; ++kk) {
      float4 a = h4[kk];
      aI += a.x * w[kk * 4 + 0] + a.y * w[kk * 4 + 1] +
            a.z * w[kk * 4 + 2] + a.w * w[kk * 4 + 3];
    }
    hs2[li * 32 + j] += invI * aI;
  }
  // ---- phase R: += h1 @ Wr, then ReLU ----
#pragma unroll
  for (int k = 0; k < 32; ++k) w[k] = Wr[k * 32 + j];
#pragma unroll
  for (int it = 0; it < CN / 8; ++it) {
    int li = it * 8 + ln;
    float aR = 0.f;
    const float4* h4 = (const float4*)(hRs + li * 32);
#pragma unroll
    for (int kk = 0; kk < 8; ++kk) {
      float4 a = h4[kk];
      aR += a.x * w[kk * 4 + 0] + a.y * w[kk * 4 + 1] +
            a.z * w[kk * 4 + 2] + a.w * w[kk * 4 + 3];
    }
    hs2[li * 32 + j] = fmaxf(hs2[li * 32 + j] + aR, 0.0f);
  }
  __syncthreads();
  if (t < 224) {
#pragma unroll
    for (int pass = 0; pass < CN * 7 / 224; ++pass) {
      int o = pass * 224 + t;
      int m = o / 7, jc = o - m * 7;
      int n = node0 + m;
      if (n < N) {
        float a = sbc[jc];
        const float* hp = hs2 + m * 32;
#pragma unroll
        for (int k = 0; k < 32; ++k) a += hp[k] * sWc[k * 7 + jc];
        out[(size_t)n * 7 + jc] = a;
      }
    }
  }
}

extern "C" void kernel_launch(void* const* d_in, const int* in_sizes, int n_in,
                              void* d_out, int out_size, void* d_ws,
                              size_t ws_size, hipStream_t stream) {
  const float* x   = (const float*)d_in[0];
  const int* ei_t  = (const int*)d_in[1];
  const int* ei_i  = (const int*)d_in[2];
  const float* W1t = (const float*)d_in[3];
  const float* b1t = (const float*)d_in[4];
  const float* W1i = (const float*)d_in[5];
  const float* b1i = (const float*)d_in[6];
  const float* W1r = (const float*)d_in[7];
  const float* b1r = (const float*)d_in[8];
  const float* W2t = (const float*)d_in[9];
  const float* b2t = (const float*)d_in[10];
  const float* W2i = (const float*)d_in[11];
  const float* b2i = (const float*)d_in[12];
  const float* W2r = (const float*)d_in[13];
  const float* b2r = (const float*)d_in[14];
  const float* Wc  = (const float*)d_in[15];
  const float* bc  = (const float*)d_in[16];
  float* out = (float*)d_out;

  const int N  = in_sizes[0] / 6;
  const int E  = in_sizes[1] / 2;
  const int Ei = in_sizes[2] / 2;
  const int K  = (N + RN - 1) / RN;
  const int halfN = N >> 1;   // halves must fit ushort: N <= 131070

  float* aggT = (float*)d_ws;
  float* aggI = aggT + (size_t)N * 32;
  unsigned short* h1b = (unsigned short*)(aggI + (size_t)N * 32);
  unsigned short* xp  = h1b + (size_t)N * 32;
  int* curT   = (int*)(xp + (size_t)N * 8);
  int* curI   = curT + KMAX;
  int4* metaT = (int4*)(curI + KMAX);
  int4* metaI = metaT + N;
  int* binT   = (int*)(metaI + N);
  int* binI   = binT + (size_t)K * CAP;
  unsigned short* csrT = (unsigned short*)(binI + (size_t)K * CAP);
  unsigned short* csrI = csrT + (size_t)K * CAP;

  const int gN8  = (N * 8 + BLK - 1) / BLK;
  const int gG1  = (N + GN1 - 1) / GN1;
  const int gG2  = (N * 4 + BLK - 1) / BLK;
  const int gC2  = (N + CN - 1) / CN;
  const int Emax = (E > Ei) ? E : Ei;
  const int gBin = (Emax + CHUNK - 1) / CHUNK;

  // ---- build ----
  k_prep<<<gN8, BLK, 0, stream>>>(x, xp, curT, curI, N, K);
  k_bin3<<<dim3(gBin, 2), BBLK, 0, stream>>>(ei_t, E, curT, binT, ei_i, Ei,
                                             curI, binI, K);
  k_sortcsr2m<<<dim3(K, 2), 512, 0, stream>>>(binT, curT, csrT, metaT, binI,
                                              curI, csrI, metaI, N, halfN);

  // ---- Layer 1 (fused gather+transform -> bf16 h1, LDS csr staging) ----
  k_g1c1<<<gG1, BLK, 0, stream>>>(xp, x, metaT, csrT, metaI, csrI, W1t, b1t,
                                  W1i, b1i, W1r, b1r, h1b, N, halfN);

  // ---- Layer 2 (src-half phased gather, then combine v4 + cls) ----
  k_gather2<<<dim3(gG2, 2), BLK, 0, stream>>>(h1b, metaT, csrT, metaI, csrI,
                                              aggT, aggI, N, halfN);
  k_combine2cls<<<gC2, BLK, 0, stream>>>(aggT, aggI, h1b, metaT, metaI, W2t,
                                         b2t, W2i, b2i, W2r, b2r, Wc, bc, out,
                                         N);
}